// Round 4
// baseline (217.150 us; speedup 1.0000x reference)
//
#include <hip/hip_runtime.h>
#include <math.h>

constexpr int C  = 128;
constexpr int HH = 28;
constexpr int HW = 784;   // 28*28

// --- repack w2/a2 from [co][ci][kh][kw] to [k=kh*3+kw][ci][co] ---
__global__ __launch_bounds__(256) void reorder_w(const float* __restrict__ w2,
                                                 const float* __restrict__ a2,
                                                 float* __restrict__ w2r,
                                                 float* __restrict__ a2r) {
    int idx = blockIdx.x * 256 + threadIdx.x;
    const int total = C * C * 9;
    const float* src = w2;
    float* dst = w2r;
    if (idx >= total) { idx -= total; src = a2; dst = a2r; }
    if (idx >= total) return;
    int co = idx & 127;
    int ci = (idx >> 7) & 127;
    int k  = idx >> 14;               // 0..8
    dst[idx] = src[(co * C + ci) * 9 + k];
}

// --- stage 1: conv1x1 + adder1x1 + BN1 + ReLU -> t1 ---
// grid: 392 blocks (4 n * 98 tiles of 8 pixels), 512 threads
__global__ __launch_bounds__(512, 4) void stage1(const float* __restrict__ x,
                                              const float* __restrict__ w1,
                                              const float* __restrict__ a1,
                                              const float* __restrict__ g1,
                                              const float* __restrict__ b1,
                                              const float* __restrict__ m1,
                                              const float* __restrict__ v1,
                                              float* __restrict__ t1) {
    __shared__ float Xs[8][132];          // [pixel][ci] then reused as [pixel][co]
    __shared__ float Rs[3][16][8][8];     // [ciq-1][cog][p][j]
    int blk = blockIdx.x;
    int n  = blk / 98;
    int q0 = (blk % 98) * 8;
    int t  = threadIdx.x;
    int p   = t & 7;
    int cog = (t >> 3) & 15;
    int ciq = t >> 7;                     // 0..3
    int cob = cog * 8;
    int ci0 = ciq * 32;

    const float* xn = x + n * C * HW;
    for (int e = t; e < 8 * C; e += 512) {
        int ci = e >> 3, pp = e & 7;
        Xs[pp][ci] = xn[ci * HW + q0 + pp];
    }
    __syncthreads();

    float acc[8];
#pragma unroll
    for (int j = 0; j < 8; ++j) acc[j] = 0.f;
    for (int ci = ci0; ci < ci0 + 32; ci += 4) {
        float4 xv = *reinterpret_cast<const float4*>(&Xs[p][ci]);
#pragma unroll
        for (int j = 0; j < 8; ++j) {
            float4 wv = *reinterpret_cast<const float4*>(&w1[(cob + j) * C + ci]);
            acc[j] = fmaf(xv.x, wv.x, acc[j]);
            acc[j] = fmaf(xv.y, wv.y, acc[j]);
            acc[j] = fmaf(xv.z, wv.z, acc[j]);
            acc[j] = fmaf(xv.w, wv.w, acc[j]);
        }
    }
    if (ciq) {
        *reinterpret_cast<float4*>(&Rs[ciq - 1][cog][p][0]) = make_float4(acc[0], acc[1], acc[2], acc[3]);
        *reinterpret_cast<float4*>(&Rs[ciq - 1][cog][p][4]) = make_float4(acc[4], acc[5], acc[6], acc[7]);
    }
    __syncthreads();                      // #1: conv partials ready, Xs reads done
    if (ciq == 0) {
#pragma unroll
        for (int q = 0; q < 3; ++q) {
            float4 r0 = *reinterpret_cast<const float4*>(&Rs[q][cog][p][0]);
            float4 r1 = *reinterpret_cast<const float4*>(&Rs[q][cog][p][4]);
            acc[0] += r0.x; acc[1] += r0.y; acc[2] += r0.z; acc[3] += r0.w;
            acc[4] += r1.x; acc[5] += r1.y; acc[6] += r1.z; acc[7] += r1.w;
        }
#pragma unroll
        for (int j = 0; j < 8; ++j) Xs[p][cob + j] = acc[j];  // conv output -> Xs
    }
    __syncthreads();                      // #2: conv output staged

    float ad[8];
#pragma unroll
    for (int j = 0; j < 8; ++j) ad[j] = 0.f;
    for (int ci = ci0; ci < ci0 + 32; ci += 4) {
        float4 yv = *reinterpret_cast<const float4*>(&Xs[p][ci]);
#pragma unroll
        for (int j = 0; j < 8; ++j) {
            float4 av = *reinterpret_cast<const float4*>(&a1[(cob + j) * C + ci]);
            ad[j] += fabsf(yv.x - av.x) + fabsf(yv.y - av.y)
                   + fabsf(yv.z - av.z) + fabsf(yv.w - av.w);
        }
    }
    if (ciq) {
        *reinterpret_cast<float4*>(&Rs[ciq - 1][cog][p][0]) = make_float4(ad[0], ad[1], ad[2], ad[3]);
        *reinterpret_cast<float4*>(&Rs[ciq - 1][cog][p][4]) = make_float4(ad[4], ad[5], ad[6], ad[7]);
    }
    __syncthreads();                      // #3: adder partials ready
    if (ciq == 0) {
#pragma unroll
        for (int q = 0; q < 3; ++q) {
            float4 r0 = *reinterpret_cast<const float4*>(&Rs[q][cog][p][0]);
            float4 r1 = *reinterpret_cast<const float4*>(&Rs[q][cog][p][4]);
            ad[0] += r0.x; ad[1] += r0.y; ad[2] += r0.z; ad[3] += r0.w;
            ad[4] += r1.x; ad[5] += r1.y; ad[6] += r1.z; ad[7] += r1.w;
        }
#pragma unroll
        for (int j = 0; j < 8; ++j) {
            int co = cob + j;
            float inv = g1[co] / sqrtf(v1[co] + 1e-5f);
            float off = b1[co] - m1[co] * inv;
            float z = fmaxf(-ad[j] * inv + off, 0.f);
            t1[(n * C + co) * HW + q0 + p] = z;
        }
    }
}

// --- stage 2: conv3x3 pad 1 -> t2 ---
// grid: 896 blocks = nh(112) * cot(8, 16 co each), 256 threads
// thread = p(32) x cog(4, 4 co each) x ciq(2, 64 ci each)
// double-buffered register prefetch of weights (9 float4 per buffer)
__global__ __launch_bounds__(256, 4) void conv3x3(const float* __restrict__ t1,
                                               const float* __restrict__ w2r,
                                               float* __restrict__ t2) {
    __shared__ float Xs[C][3][32];    // [ci][row][w+1], zero-padded halo (48KB)
    __shared__ float Rs[4][32][4];    // partials from ciq=1 (2KB)
    int blk = blockIdx.x;
    int cot = blk & 7;
    int nh  = blk >> 3;
    int h   = nh % HH;
    int n   = nh / HH;
    int t   = threadIdx.x;
    int p   = t & 31;                 // output w, active p<28
    int pr  = p < 27 ? p : 27;        // clamp idle lanes
    int cog = (t >> 5) & 3;
    int ciq = t >> 7;                 // 0..1
    int co0 = cot * 16 + cog * 4;
    int ci0 = ciq * 64;

    float4* xs4 = reinterpret_cast<float4*>(&Xs[0][0][0]);
    for (int e = t; e < C * 3 * 32 / 4; e += 256) xs4[e] = make_float4(0.f, 0.f, 0.f, 0.f);
    __syncthreads();
    const float* src = t1 + n * C * HW;
    for (int e = t; e < C * 3 * 28; e += 256) {
        int ci  = e / 84;
        int rem = e - ci * 84;
        int r   = rem / 28;
        int w   = rem - r * 28;
        int hh  = h + r - 1;
        if ((unsigned)hh < 28u) Xs[ci][r][w + 1] = src[ci * HW + hh * 28 + w];
    }
    __syncthreads();

    const float* wb = w2r + co0;      // [k][ci][co]
    float4 wA[9], wB[9];
#pragma unroll
    for (int k = 0; k < 9; ++k)
        wA[k] = *reinterpret_cast<const float4*>(wb + (k * C + ci0) * C);
    float acc[4] = {0.f, 0.f, 0.f, 0.f};

    auto body = [&](int ci, const float4 (&w)[9]) {
        float xv[9];
#pragma unroll
        for (int kh = 0; kh < 3; ++kh)
#pragma unroll
            for (int kw = 0; kw < 3; ++kw) xv[kh * 3 + kw] = Xs[ci][kh][pr + kw];
#pragma unroll
        for (int k = 0; k < 9; ++k) {
            acc[0] = fmaf(xv[k], w[k].x, acc[0]);
            acc[1] = fmaf(xv[k], w[k].y, acc[1]);
            acc[2] = fmaf(xv[k], w[k].z, acc[2]);
            acc[3] = fmaf(xv[k], w[k].w, acc[3]);
        }
    };

#pragma unroll 1
    for (int ci = ci0; ci < ci0 + 64; ci += 2) {
#pragma unroll
        for (int k = 0; k < 9; ++k)
            wB[k] = *reinterpret_cast<const float4*>(wb + (k * C + ci + 1) * C);
        body(ci, wA);
        int cin = (ci + 2) & 127;     // wrap keeps last prefetch in-bounds (dummy)
#pragma unroll
        for (int k = 0; k < 9; ++k)
            wA[k] = *reinterpret_cast<const float4*>(wb + (k * C + cin) * C);
        body(ci + 1, wB);
    }

    if (ciq) *reinterpret_cast<float4*>(&Rs[cog][p][0]) = make_float4(acc[0], acc[1], acc[2], acc[3]);
    __syncthreads();
    if (ciq == 0 && p < 28) {
        float4 r = *reinterpret_cast<const float4*>(&Rs[cog][p][0]);
        acc[0] += r.x; acc[1] += r.y; acc[2] += r.z; acc[3] += r.w;
        float* dst = t2 + (n * C + co0) * HW + h * 28 + p;
#pragma unroll
        for (int j = 0; j < 4; ++j) dst[j * HW] = acc[j];
    }
}

// --- stage 3: adder3x3 pad 1 + BN2 + ReLU + residual + ReLU -> out ---
__global__ __launch_bounds__(256, 4) void adder3x3(const float* __restrict__ t2,
                                                const float* __restrict__ a2r,
                                                const float* __restrict__ x0,
                                                const float* __restrict__ g2,
                                                const float* __restrict__ b2,
                                                const float* __restrict__ m2,
                                                const float* __restrict__ v2,
                                                float* __restrict__ out) {
    __shared__ float Xs[C][3][32];
    __shared__ float Rs[4][32][4];
    int blk = blockIdx.x;
    int cot = blk & 7;
    int nh  = blk >> 3;
    int h   = nh % HH;
    int n   = nh / HH;
    int t   = threadIdx.x;
    int p   = t & 31;
    int pr  = p < 27 ? p : 27;
    int cog = (t >> 5) & 3;
    int ciq = t >> 7;
    int co0 = cot * 16 + cog * 4;
    int ci0 = ciq * 64;

    float4* xs4 = reinterpret_cast<float4*>(&Xs[0][0][0]);
    for (int e = t; e < C * 3 * 32 / 4; e += 256) xs4[e] = make_float4(0.f, 0.f, 0.f, 0.f);
    __syncthreads();
    const float* src = t2 + n * C * HW;
    for (int e = t; e < C * 3 * 28; e += 256) {
        int ci  = e / 84;
        int rem = e - ci * 84;
        int r   = rem / 28;
        int w   = rem - r * 28;
        int hh  = h + r - 1;
        if ((unsigned)hh < 28u) Xs[ci][r][w + 1] = src[ci * HW + hh * 28 + w];
    }
    __syncthreads();

    const float* ab = a2r + co0;      // [k][ci][co]
    float4 wA[9], wB[9];
#pragma unroll
    for (int k = 0; k < 9; ++k)
        wA[k] = *reinterpret_cast<const float4*>(ab + (k * C + ci0) * C);
    float acc[4] = {0.f, 0.f, 0.f, 0.f};

    auto body = [&](int ci, const float4 (&w)[9]) {
        float xv[9];
#pragma unroll
        for (int kh = 0; kh < 3; ++kh)
#pragma unroll
            for (int kw = 0; kw < 3; ++kw) xv[kh * 3 + kw] = Xs[ci][kh][pr + kw];
#pragma unroll
        for (int k = 0; k < 9; ++k) {
            acc[0] += fabsf(xv[k] - w[k].x);
            acc[1] += fabsf(xv[k] - w[k].y);
            acc[2] += fabsf(xv[k] - w[k].z);
            acc[3] += fabsf(xv[k] - w[k].w);
        }
    };

#pragma unroll 1
    for (int ci = ci0; ci < ci0 + 64; ci += 2) {
#pragma unroll
        for (int k = 0; k < 9; ++k)
            wB[k] = *reinterpret_cast<const float4*>(ab + (k * C + ci + 1) * C);
        body(ci, wA);
        int cin = (ci + 2) & 127;
#pragma unroll
        for (int k = 0; k < 9; ++k)
            wA[k] = *reinterpret_cast<const float4*>(ab + (k * C + cin) * C);
        body(ci + 1, wB);
    }

    if (ciq) *reinterpret_cast<float4*>(&Rs[cog][p][0]) = make_float4(acc[0], acc[1], acc[2], acc[3]);
    __syncthreads();
    if (ciq == 0 && p < 28) {
        float4 r = *reinterpret_cast<const float4*>(&Rs[cog][p][0]);
        acc[0] += r.x; acc[1] += r.y; acc[2] += r.z; acc[3] += r.w;
        int base = (n * C + co0) * HW + h * 28 + p;
#pragma unroll
        for (int j = 0; j < 4; ++j) {
            int co = co0 + j;
            float inv = g2[co] / sqrtf(v2[co] + 1e-5f);
            float off = b2[co] - m2[co] * inv;
            float z = fmaxf(-acc[j] * inv + off, 0.f);
            z += x0[base + j * HW];
            out[base + j * HW] = fmaxf(z, 0.f);
        }
    }
}

extern "C" void kernel_launch(void* const* d_in, const int* in_sizes, int n_in,
                              void* d_out, int out_size, void* d_ws, size_t ws_size,
                              hipStream_t stream) {
    const float* x   = (const float*)d_in[0];
    const float* w1  = (const float*)d_in[1];   // w_shift1 (C,C,1,1)
    const float* a1  = (const float*)d_in[2];   // w_add1   (C,C,1,1)
    const float* g1  = (const float*)d_in[3];
    const float* b1  = (const float*)d_in[4];
    const float* m1  = (const float*)d_in[5];
    const float* v1  = (const float*)d_in[6];
    const float* w2  = (const float*)d_in[7];   // w_shift2 (C,C,3,3)
    const float* a2  = (const float*)d_in[8];   // w_add2   (C,C,3,3)
    const float* g2  = (const float*)d_in[9];
    const float* b2  = (const float*)d_in[10];
    const float* m2  = (const float*)d_in[11];
    const float* v2  = (const float*)d_in[12];
    float* out = (float*)d_out;

    float* ws  = (float*)d_ws;
    float* t1  = ws;                       // 401408
    float* t2  = t1 + 4 * C * HW;          // 401408
    float* w2r = t2 + 4 * C * HW;          // 147456
    float* a2r = w2r + C * C * 9;          // 147456

    const int reorder_total = 2 * C * C * 9;
    reorder_w<<<(reorder_total + 255) / 256, 256, 0, stream>>>(w2, a2, w2r, a2r);
    stage1<<<392, 512, 0, stream>>>(x, w1, a1, g1, b1, m1, v1, t1);
    conv3x3<<<896, 256, 0, stream>>>(t1, w2r, t2);
    adder3x3<<<896, 256, 0, stream>>>(t2, a2r, x, g2, b2, m2, v2, out);
}

// Round 5
// 97.056 us; speedup vs baseline: 2.2374x; 2.2374x over previous
//
#include <hip/hip_runtime.h>
#include <math.h>

constexpr int C  = 128;
constexpr int HH = 28;
constexpr int HW = 784;   // 28*28

// --- repack: w2/a2 [co][ci][kh][kw] -> [k][ci][co]; w1/a1 [co][ci] -> [ci][co] ---
__global__ __launch_bounds__(256) void reorder_w(const float* __restrict__ w2,
                                                 const float* __restrict__ a2,
                                                 const float* __restrict__ w1,
                                                 const float* __restrict__ a1,
                                                 float* __restrict__ w2r,
                                                 float* __restrict__ a2r,
                                                 float* __restrict__ w1r,
                                                 float* __restrict__ a1r) {
    int idx = blockIdx.x * 256 + threadIdx.x;
    const int T9 = C * C * 9;   // 147456
    const int T1 = C * C;       // 16384
    if (idx < 2 * T9) {
        const float* src = w2; float* dst = w2r;
        if (idx >= T9) { idx -= T9; src = a2; dst = a2r; }
        int co = idx & 127;
        int ci = (idx >> 7) & 127;
        int k  = idx >> 14;               // 0..8
        dst[idx] = src[(co * C + ci) * 9 + k];   // dst = [k][ci][co]
        return;
    }
    idx -= 2 * T9;
    if (idx >= 2 * T1) return;
    const float* src = w1; float* dst = w1r;
    if (idx >= T1) { idx -= T1; src = a1; dst = a1r; }
    int co = idx & 127;
    int ci = idx >> 7;
    dst[idx] = src[co * C + ci];          // dst = [ci][co]
}

// --- stage 1: conv1x1 + adder1x1 + BN1 + ReLU -> t1 ---
// grid: 784 = n(4) x tile(196, 4 px each); 512 threads = co(128) x ciq(4, 32 ci)
__global__ __launch_bounds__(512, 4) void stage1(const float* __restrict__ x,
                                                 const float* __restrict__ w1r,
                                                 const float* __restrict__ a1r,
                                                 const float* __restrict__ g1,
                                                 const float* __restrict__ b1,
                                                 const float* __restrict__ m1,
                                                 const float* __restrict__ v1,
                                                 float* __restrict__ t1) {
    __shared__ float Xs[C][4];        // input pixels [ci][px]
    __shared__ float Ys[C][4];        // conv1x1 output [co][px]
    __shared__ float Rs[3][C][4];     // ciq partials
    int blk = blockIdx.x;
    int n   = blk / 196;
    int px0 = (blk % 196) * 4;
    int t   = threadIdx.x;
    int co  = t & 127;
    int ciq = t >> 7;                 // 0..3
    int ci0 = ciq * 32;

    // stage x tile: 512 elems, one per thread
    {
        int ci = t >> 2, p = t & 3;
        Xs[ci][p] = x[(n * C + ci) * HW + px0 + p];
    }
    __syncthreads();

    float4 acc = make_float4(0.f, 0.f, 0.f, 0.f);
#pragma unroll 4
    for (int ci = ci0; ci < ci0 + 32; ++ci) {
        float wv = w1r[ci * C + co];                              // coalesced
        float4 xv = *reinterpret_cast<const float4*>(&Xs[ci][0]); // broadcast
        acc.x = fmaf(xv.x, wv, acc.x);
        acc.y = fmaf(xv.y, wv, acc.y);
        acc.z = fmaf(xv.z, wv, acc.z);
        acc.w = fmaf(xv.w, wv, acc.w);
    }
    if (ciq) *reinterpret_cast<float4*>(&Rs[ciq - 1][co][0]) = acc;
    __syncthreads();
    if (ciq == 0) {
#pragma unroll
        for (int q = 0; q < 3; ++q) {
            float4 r = *reinterpret_cast<const float4*>(&Rs[q][co][0]);
            acc.x += r.x; acc.y += r.y; acc.z += r.z; acc.w += r.w;
        }
        *reinterpret_cast<float4*>(&Ys[co][0]) = acc;
    }
    __syncthreads();

    float4 ad = make_float4(0.f, 0.f, 0.f, 0.f);
#pragma unroll 4
    for (int ci = ci0; ci < ci0 + 32; ++ci) {
        float av = a1r[ci * C + co];                              // coalesced
        float4 yv = *reinterpret_cast<const float4*>(&Ys[ci][0]); // broadcast
        ad.x += fabsf(yv.x - av);
        ad.y += fabsf(yv.y - av);
        ad.z += fabsf(yv.z - av);
        ad.w += fabsf(yv.w - av);
    }
    if (ciq) *reinterpret_cast<float4*>(&Rs[ciq - 1][co][0]) = ad;
    __syncthreads();
    if (ciq == 0) {
#pragma unroll
        for (int q = 0; q < 3; ++q) {
            float4 r = *reinterpret_cast<const float4*>(&Rs[q][co][0]);
            ad.x += r.x; ad.y += r.y; ad.z += r.z; ad.w += r.w;
        }
        float inv = g1[co] / sqrtf(v1[co] + 1e-5f);
        float off = b1[co] - m1[co] * inv;
        float4 z;
        z.x = fmaxf(-ad.x * inv + off, 0.f);
        z.y = fmaxf(-ad.y * inv + off, 0.f);
        z.z = fmaxf(-ad.z * inv + off, 0.f);
        z.w = fmaxf(-ad.w * inv + off, 0.f);
        *reinterpret_cast<float4*>(&t1[(n * C + co) * HW + px0]) = z;
    }
}

// --- stage 2: conv3x3 pad 1 -> t2 ---
// grid: 784 = n(4) x tile(196: h(28) x wq(7)); 512 threads = co(128) x ciq(4, 32 ci)
// weights: coalesced b32 streams; x: wave-uniform LDS broadcast from 9KB halo tile
__global__ __launch_bounds__(512, 4) void conv3x3(const float* __restrict__ t1,
                                                  const float* __restrict__ w2r,
                                                  float* __restrict__ t2) {
    __shared__ float Xs[C][3][8];     // [ci][row][col], 6 cols used
    __shared__ float Rs[3][C][4];
    int blk = blockIdx.x;
    int n    = blk / 196;
    int tile = blk % 196;
    int h    = tile / 7;
    int w0   = (tile % 7) * 4;
    int t   = threadIdx.x;
    int co  = t & 127;
    int ciq = t >> 7;
    int ci0 = ciq * 32;

    const float* src = t1 + n * C * HW;
    for (int e = t; e < C * 3 * 6; e += 512) {
        int ci  = e / 18;
        int rem = e - ci * 18;
        int r   = rem / 6;
        int c   = rem - r * 6;
        int hh  = h + r - 1, ww = w0 + c - 1;
        float v = 0.f;
        if ((unsigned)hh < 28u && (unsigned)ww < 28u) v = src[ci * HW + hh * 28 + ww];
        Xs[ci][r][c] = v;
    }
    __syncthreads();

    float4 acc = make_float4(0.f, 0.f, 0.f, 0.f);
#pragma unroll 2
    for (int ci = ci0; ci < ci0 + 32; ++ci) {
        float wk[9];
#pragma unroll
        for (int k = 0; k < 9; ++k) wk[k] = w2r[(k * C + ci) * C + co];  // coalesced
        float xr[3][6];
#pragma unroll
        for (int r = 0; r < 3; ++r) {
            float4 lo = *reinterpret_cast<const float4*>(&Xs[ci][r][0]); // broadcast
            float2 hi = *reinterpret_cast<const float2*>(&Xs[ci][r][4]);
            xr[r][0] = lo.x; xr[r][1] = lo.y; xr[r][2] = lo.z; xr[r][3] = lo.w;
            xr[r][4] = hi.x; xr[r][5] = hi.y;
        }
#pragma unroll
        for (int r = 0; r < 3; ++r)
#pragma unroll
            for (int kw = 0; kw < 3; ++kw) {
                float wv = wk[r * 3 + kw];
                acc.x = fmaf(xr[r][kw + 0], wv, acc.x);
                acc.y = fmaf(xr[r][kw + 1], wv, acc.y);
                acc.z = fmaf(xr[r][kw + 2], wv, acc.z);
                acc.w = fmaf(xr[r][kw + 3], wv, acc.w);
            }
    }
    if (ciq) *reinterpret_cast<float4*>(&Rs[ciq - 1][co][0]) = acc;
    __syncthreads();
    if (ciq == 0) {
#pragma unroll
        for (int q = 0; q < 3; ++q) {
            float4 r = *reinterpret_cast<const float4*>(&Rs[q][co][0]);
            acc.x += r.x; acc.y += r.y; acc.z += r.z; acc.w += r.w;
        }
        *reinterpret_cast<float4*>(&t2[(n * C + co) * HW + h * 28 + w0]) = acc;
    }
}

// --- stage 3: adder3x3 pad 1 + BN2 + ReLU + residual + ReLU -> out ---
__global__ __launch_bounds__(512, 4) void adder3x3(const float* __restrict__ t2,
                                                   const float* __restrict__ a2r,
                                                   const float* __restrict__ x0,
                                                   const float* __restrict__ g2,
                                                   const float* __restrict__ b2,
                                                   const float* __restrict__ m2,
                                                   const float* __restrict__ v2,
                                                   float* __restrict__ out) {
    __shared__ float Xs[C][3][8];
    __shared__ float Rs[3][C][4];
    int blk = blockIdx.x;
    int n    = blk / 196;
    int tile = blk % 196;
    int h    = tile / 7;
    int w0   = (tile % 7) * 4;
    int t   = threadIdx.x;
    int co  = t & 127;
    int ciq = t >> 7;
    int ci0 = ciq * 32;

    const float* src = t2 + n * C * HW;
    for (int e = t; e < C * 3 * 6; e += 512) {
        int ci  = e / 18;
        int rem = e - ci * 18;
        int r   = rem / 6;
        int c   = rem - r * 6;
        int hh  = h + r - 1, ww = w0 + c - 1;
        float v = 0.f;
        if ((unsigned)hh < 28u && (unsigned)ww < 28u) v = src[ci * HW + hh * 28 + ww];
        Xs[ci][r][c] = v;
    }
    __syncthreads();

    float4 acc = make_float4(0.f, 0.f, 0.f, 0.f);
#pragma unroll 2
    for (int ci = ci0; ci < ci0 + 32; ++ci) {
        float wk[9];
#pragma unroll
        for (int k = 0; k < 9; ++k) wk[k] = a2r[(k * C + ci) * C + co];
        float xr[3][6];
#pragma unroll
        for (int r = 0; r < 3; ++r) {
            float4 lo = *reinterpret_cast<const float4*>(&Xs[ci][r][0]);
            float2 hi = *reinterpret_cast<const float2*>(&Xs[ci][r][4]);
            xr[r][0] = lo.x; xr[r][1] = lo.y; xr[r][2] = lo.z; xr[r][3] = lo.w;
            xr[r][4] = hi.x; xr[r][5] = hi.y;
        }
#pragma unroll
        for (int r = 0; r < 3; ++r)
#pragma unroll
            for (int kw = 0; kw < 3; ++kw) {
                float wv = wk[r * 3 + kw];
                acc.x += fabsf(xr[r][kw + 0] - wv);
                acc.y += fabsf(xr[r][kw + 1] - wv);
                acc.z += fabsf(xr[r][kw + 2] - wv);
                acc.w += fabsf(xr[r][kw + 3] - wv);
            }
    }
    if (ciq) *reinterpret_cast<float4*>(&Rs[ciq - 1][co][0]) = acc;
    __syncthreads();
    if (ciq == 0) {
#pragma unroll
        for (int q = 0; q < 3; ++q) {
            float4 r = *reinterpret_cast<const float4*>(&Rs[q][co][0]);
            acc.x += r.x; acc.y += r.y; acc.z += r.z; acc.w += r.w;
        }
        float inv = g2[co] / sqrtf(v2[co] + 1e-5f);
        float off = b2[co] - m2[co] * inv;
        int base = (n * C + co) * HW + h * 28 + w0;
        float4 id = *reinterpret_cast<const float4*>(&x0[base]);
        float4 z;
        z.x = fmaxf(fmaxf(-acc.x * inv + off, 0.f) + id.x, 0.f);
        z.y = fmaxf(fmaxf(-acc.y * inv + off, 0.f) + id.y, 0.f);
        z.z = fmaxf(fmaxf(-acc.z * inv + off, 0.f) + id.z, 0.f);
        z.w = fmaxf(fmaxf(-acc.w * inv + off, 0.f) + id.w, 0.f);
        *reinterpret_cast<float4*>(&out[base]) = z;
    }
}

extern "C" void kernel_launch(void* const* d_in, const int* in_sizes, int n_in,
                              void* d_out, int out_size, void* d_ws, size_t ws_size,
                              hipStream_t stream) {
    const float* x   = (const float*)d_in[0];
    const float* w1  = (const float*)d_in[1];   // w_shift1 (C,C,1,1)
    const float* a1  = (const float*)d_in[2];   // w_add1   (C,C,1,1)
    const float* g1  = (const float*)d_in[3];
    const float* b1  = (const float*)d_in[4];
    const float* m1  = (const float*)d_in[5];
    const float* v1  = (const float*)d_in[6];
    const float* w2  = (const float*)d_in[7];   // w_shift2 (C,C,3,3)
    const float* a2  = (const float*)d_in[8];   // w_add2   (C,C,3,3)
    const float* g2  = (const float*)d_in[9];
    const float* b2  = (const float*)d_in[10];
    const float* m2  = (const float*)d_in[11];
    const float* v2  = (const float*)d_in[12];
    float* out = (float*)d_out;

    float* ws  = (float*)d_ws;
    float* t1  = ws;                       // 401408
    float* t2  = t1 + 4 * C * HW;          // 401408
    float* w2r = t2 + 4 * C * HW;          // 147456
    float* a2r = w2r + C * C * 9;          // 147456
    float* w1r = a2r + C * C * 9;          // 16384
    float* a1r = w1r + C * C;              // 16384

    const int reorder_total = 2 * C * C * 9 + 2 * C * C;
    reorder_w<<<(reorder_total + 255) / 256, 256, 0, stream>>>(w2, a2, w1, a1, w2r, a2r, w1r, a1r);
    stage1<<<784, 512, 0, stream>>>(x, w1r, a1r, g1, b1, m1, v1, t1);
    conv3x3<<<784, 512, 0, stream>>>(t1, w2r, t2);
    adder3x3<<<784, 512, 0, stream>>>(t2, a2r, x, g2, b2, m2, v2, out);
}

// Round 6
// 91.905 us; speedup vs baseline: 2.3628x; 1.0560x over previous
//
#include <hip/hip_runtime.h>
#include <math.h>

constexpr int C  = 128;
constexpr int HW = 784;   // 28*28

// --- repack: w2/a2 [co][ci][kh][kw] -> [ci][k][co]; w1/a1 [co][ci] -> [ci][co] ---
__global__ __launch_bounds__(256) void reorder_w(const float* __restrict__ w2,
                                                 const float* __restrict__ a2,
                                                 const float* __restrict__ w1,
                                                 const float* __restrict__ a1,
                                                 float* __restrict__ w2r,
                                                 float* __restrict__ a2r,
                                                 float* __restrict__ w1r,
                                                 float* __restrict__ a1r) {
    int idx = blockIdx.x * 256 + threadIdx.x;
    const int T9 = C * C * 9;   // 147456
    const int T1 = C * C;       // 16384
    if (idx < 2 * T9) {
        const float* src = w2; float* dst = w2r;
        if (idx >= T9) { idx -= T9; src = a2; dst = a2r; }
        int co = idx & 127;
        int r  = idx >> 7;                // ci*9 + k
        int k  = r % 9;
        int ci = r / 9;
        dst[idx] = src[(co * C + ci) * 9 + k];
        return;
    }
    idx -= 2 * T9;
    if (idx >= 2 * T1) return;
    const float* src = w1; float* dst = w1r;
    if (idx >= T1) { idx -= T1; src = a1; dst = a1r; }
    int co = idx & 127;
    int ci = idx >> 7;
    dst[idx] = src[co * C + ci];          // [ci][co]
}

// --- stage 1: conv1x1 + adder1x1 + BN1 + ReLU -> t1 ---
// grid: 784 = n(4) x tile(196, 4 px each); 1024 threads = co(128) x ciq(8, 16 ci)
__global__ __launch_bounds__(1024, 8) void stage1(const float* __restrict__ x,
                                                  const float* __restrict__ w1r,
                                                  const float* __restrict__ a1r,
                                                  const float* __restrict__ g1,
                                                  const float* __restrict__ b1,
                                                  const float* __restrict__ m1,
                                                  const float* __restrict__ v1,
                                                  float* __restrict__ t1) {
    __shared__ float Xs[C][4];        // input pixels [ci][px]
    __shared__ float Ys[C][4];        // conv1x1 output [co][px]
    __shared__ float Rs[7][C][4];     // ciq partials
    int blk = blockIdx.x;
    int n   = blk / 196;
    int px0 = (blk % 196) * 4;
    int t   = threadIdx.x;
    int co  = t & 127;
    int ciq = t >> 7;                 // 0..7
    int ci0 = ciq * 16;

    if (t < 512) {
        int ci = t >> 2, p = t & 3;
        Xs[ci][p] = x[(n * C + ci) * HW + px0 + p];
    }
    __syncthreads();

    float4 acc = make_float4(0.f, 0.f, 0.f, 0.f);
    const float* wp = w1r + co;
#pragma unroll
    for (int i = 0; i < 16; ++i) {
        int ci = ci0 + i;
        float wv = wp[ci * C];                                    // coalesced
        float4 xv = *reinterpret_cast<const float4*>(&Xs[ci][0]); // broadcast
        acc.x = fmaf(xv.x, wv, acc.x);
        acc.y = fmaf(xv.y, wv, acc.y);
        acc.z = fmaf(xv.z, wv, acc.z);
        acc.w = fmaf(xv.w, wv, acc.w);
    }
    if (ciq) *reinterpret_cast<float4*>(&Rs[ciq - 1][co][0]) = acc;
    __syncthreads();                  // A
    if (ciq == 0) {
#pragma unroll
        for (int q = 0; q < 7; ++q) {
            float4 r = *reinterpret_cast<const float4*>(&Rs[q][co][0]);
            acc.x += r.x; acc.y += r.y; acc.z += r.z; acc.w += r.w;
        }
        *reinterpret_cast<float4*>(&Ys[co][0]) = acc;
    }
    __syncthreads();                  // B

    float4 ad = make_float4(0.f, 0.f, 0.f, 0.f);
    const float* ap = a1r + co;
#pragma unroll
    for (int i = 0; i < 16; ++i) {
        int ci = ci0 + i;
        float av = ap[ci * C];
        float4 yv = *reinterpret_cast<const float4*>(&Ys[ci][0]);
        ad.x += fabsf(yv.x - av);
        ad.y += fabsf(yv.y - av);
        ad.z += fabsf(yv.z - av);
        ad.w += fabsf(yv.w - av);
    }
    if (ciq) *reinterpret_cast<float4*>(&Rs[ciq - 1][co][0]) = ad;
    __syncthreads();                  // C
    if (ciq == 0) {
#pragma unroll
        for (int q = 0; q < 7; ++q) {
            float4 r = *reinterpret_cast<const float4*>(&Rs[q][co][0]);
            ad.x += r.x; ad.y += r.y; ad.z += r.z; ad.w += r.w;
        }
        float inv = g1[co] / sqrtf(v1[co] + 1e-5f);
        float off = b1[co] - m1[co] * inv;
        float4 z;
        z.x = fmaxf(-ad.x * inv + off, 0.f);
        z.y = fmaxf(-ad.y * inv + off, 0.f);
        z.z = fmaxf(-ad.z * inv + off, 0.f);
        z.w = fmaxf(-ad.w * inv + off, 0.f);
        *reinterpret_cast<float4*>(&t1[(n * C + co) * HW + px0]) = z;
    }
}

// --- stage 2: conv3x3 pad 1 -> t2 ---
// grid: 784 = n(4) x th(14) x tw(14), 2x2 output tile per block
// 1024 threads = co(128) x ciq(8, 16 ci each)
__global__ __launch_bounds__(1024, 8) void conv3x3(const float* __restrict__ t1,
                                                   const float* __restrict__ w2r,
                                                   float* __restrict__ t2) {
    __shared__ float Xs[C][4][4];     // [ci][row][col] halo, b128 rows
    __shared__ float Rs[7][C][4];
    int blk = blockIdx.x;
    int n    = blk / 196;
    int tile = blk % 196;
    int th   = tile / 14;
    int tw   = tile % 14;
    int h0   = th * 2;
    int w0   = tw * 2;
    int t   = threadIdx.x;
    int co  = t & 127;
    int ciq = t >> 7;                 // 0..7
    int ci0 = ciq * 16;

    const float* src = t1 + n * C * HW;
#pragma unroll
    for (int e = t; e < C * 16; e += 1024) {   // 2 iters
        int ci = e >> 4, r = (e >> 2) & 3, c = e & 3;
        int hh = h0 + r - 1, ww = w0 + c - 1;
        float v = 0.f;
        if ((unsigned)hh < 28u && (unsigned)ww < 28u) v = src[ci * HW + hh * 28 + ww];
        Xs[ci][r][c] = v;
    }
    __syncthreads();

    float a00 = 0.f, a01 = 0.f, a10 = 0.f, a11 = 0.f;
    const float* wb = w2r + co;       // [ci][k][co]
#pragma unroll 2
    for (int ci = ci0; ci < ci0 + 16; ++ci) {
        const float* wp = wb + ci * 9 * C;
        float wk[9];
#pragma unroll
        for (int k = 0; k < 9; ++k) wk[k] = wp[k * C];            // coalesced
        float xr[4][4];
#pragma unroll
        for (int rr = 0; rr < 4; ++rr) {
            float4 q = *reinterpret_cast<const float4*>(&Xs[ci][rr][0]); // broadcast
            xr[rr][0] = q.x; xr[rr][1] = q.y; xr[rr][2] = q.z; xr[rr][3] = q.w;
        }
#pragma unroll
        for (int kh = 0; kh < 3; ++kh)
#pragma unroll
            for (int kw = 0; kw < 3; ++kw) {
                float wv = wk[kh * 3 + kw];
                a00 = fmaf(xr[kh + 0][kw + 0], wv, a00);
                a01 = fmaf(xr[kh + 0][kw + 1], wv, a01);
                a10 = fmaf(xr[kh + 1][kw + 0], wv, a10);
                a11 = fmaf(xr[kh + 1][kw + 1], wv, a11);
            }
    }
    if (ciq) *reinterpret_cast<float4*>(&Rs[ciq - 1][co][0]) = make_float4(a00, a01, a10, a11);
    __syncthreads();
    if (ciq == 0) {
#pragma unroll
        for (int q = 0; q < 7; ++q) {
            float4 r = *reinterpret_cast<const float4*>(&Rs[q][co][0]);
            a00 += r.x; a01 += r.y; a10 += r.z; a11 += r.w;
        }
        float* dst = t2 + (n * C + co) * HW + h0 * 28 + w0;
        dst[0] = a00; dst[1] = a01; dst[28] = a10; dst[29] = a11;
    }
}

// --- stage 3: adder3x3 pad 1 + BN2 + ReLU + residual + ReLU -> out ---
__global__ __launch_bounds__(1024, 8) void adder3x3(const float* __restrict__ t2,
                                                    const float* __restrict__ a2r,
                                                    const float* __restrict__ x0,
                                                    const float* __restrict__ g2,
                                                    const float* __restrict__ b2,
                                                    const float* __restrict__ m2,
                                                    const float* __restrict__ v2,
                                                    float* __restrict__ out) {
    __shared__ float Xs[C][4][4];
    __shared__ float Rs[7][C][4];
    int blk = blockIdx.x;
    int n    = blk / 196;
    int tile = blk % 196;
    int th   = tile / 14;
    int tw   = tile % 14;
    int h0   = th * 2;
    int w0   = tw * 2;
    int t   = threadIdx.x;
    int co  = t & 127;
    int ciq = t >> 7;
    int ci0 = ciq * 16;

    const float* src = t2 + n * C * HW;
#pragma unroll
    for (int e = t; e < C * 16; e += 1024) {
        int ci = e >> 4, r = (e >> 2) & 3, c = e & 3;
        int hh = h0 + r - 1, ww = w0 + c - 1;
        float v = 0.f;
        if ((unsigned)hh < 28u && (unsigned)ww < 28u) v = src[ci * HW + hh * 28 + ww];
        Xs[ci][r][c] = v;
    }
    __syncthreads();

    float a00 = 0.f, a01 = 0.f, a10 = 0.f, a11 = 0.f;
    const float* ab = a2r + co;       // [ci][k][co]
#pragma unroll 2
    for (int ci = ci0; ci < ci0 + 16; ++ci) {
        const float* wp = ab + ci * 9 * C;
        float wk[9];
#pragma unroll
        for (int k = 0; k < 9; ++k) wk[k] = wp[k * C];
        float xr[4][4];
#pragma unroll
        for (int rr = 0; rr < 4; ++rr) {
            float4 q = *reinterpret_cast<const float4*>(&Xs[ci][rr][0]);
            xr[rr][0] = q.x; xr[rr][1] = q.y; xr[rr][2] = q.z; xr[rr][3] = q.w;
        }
#pragma unroll
        for (int kh = 0; kh < 3; ++kh)
#pragma unroll
            for (int kw = 0; kw < 3; ++kw) {
                float wv = wk[kh * 3 + kw];
                a00 += fabsf(xr[kh + 0][kw + 0] - wv);
                a01 += fabsf(xr[kh + 0][kw + 1] - wv);
                a10 += fabsf(xr[kh + 1][kw + 0] - wv);
                a11 += fabsf(xr[kh + 1][kw + 1] - wv);
            }
    }
    if (ciq) *reinterpret_cast<float4*>(&Rs[ciq - 1][co][0]) = make_float4(a00, a01, a10, a11);
    __syncthreads();
    if (ciq == 0) {
#pragma unroll
        for (int q = 0; q < 7; ++q) {
            float4 r = *reinterpret_cast<const float4*>(&Rs[q][co][0]);
            a00 += r.x; a01 += r.y; a10 += r.z; a11 += r.w;
        }
        float inv = g2[co] / sqrtf(v2[co] + 1e-5f);
        float off = b2[co] - m2[co] * inv;
        int base = (n * C + co) * HW + h0 * 28 + w0;
        float z00 = fmaxf(fmaxf(-a00 * inv + off, 0.f) + x0[base + 0],  0.f);
        float z01 = fmaxf(fmaxf(-a01 * inv + off, 0.f) + x0[base + 1],  0.f);
        float z10 = fmaxf(fmaxf(-a10 * inv + off, 0.f) + x0[base + 28], 0.f);
        float z11 = fmaxf(fmaxf(-a11 * inv + off, 0.f) + x0[base + 29], 0.f);
        out[base + 0]  = z00;
        out[base + 1]  = z01;
        out[base + 28] = z10;
        out[base + 29] = z11;
    }
}

extern "C" void kernel_launch(void* const* d_in, const int* in_sizes, int n_in,
                              void* d_out, int out_size, void* d_ws, size_t ws_size,
                              hipStream_t stream) {
    const float* x   = (const float*)d_in[0];
    const float* w1  = (const float*)d_in[1];   // w_shift1 (C,C,1,1)
    const float* a1  = (const float*)d_in[2];   // w_add1   (C,C,1,1)
    const float* g1  = (const float*)d_in[3];
    const float* b1  = (const float*)d_in[4];
    const float* m1  = (const float*)d_in[5];
    const float* v1  = (const float*)d_in[6];
    const float* w2  = (const float*)d_in[7];   // w_shift2 (C,C,3,3)
    const float* a2  = (const float*)d_in[8];   // w_add2   (C,C,3,3)
    const float* g2  = (const float*)d_in[9];
    const float* b2  = (const float*)d_in[10];
    const float* m2  = (const float*)d_in[11];
    const float* v2  = (const float*)d_in[12];
    float* out = (float*)d_out;

    float* ws  = (float*)d_ws;
    float* t1  = ws;                       // 401408
    float* t2  = t1 + 4 * C * HW;          // 401408
    float* w2r = t2 + 4 * C * HW;          // 147456
    float* a2r = w2r + C * C * 9;          // 147456
    float* w1r = a2r + C * C * 9;          // 16384
    float* a1r = w1r + C * C;              // 16384

    const int reorder_total = 2 * C * C * 9 + 2 * C * C;
    reorder_w<<<(reorder_total + 255) / 256, 256, 0, stream>>>(w2, a2, w1, a1, w2r, a2r, w1r, a1r);
    stage1<<<784, 1024, 0, stream>>>(x, w1r, a1r, g1, b1, m1, v1, t1);
    conv3x3<<<784, 1024, 0, stream>>>(t1, w2r, t2);
    adder3x3<<<784, 1024, 0, stream>>>(t2, a2r, x, g2, b2, m2, v2, out);
}

// Round 7
// 89.572 us; speedup vs baseline: 2.4243x; 1.0260x over previous
//
#include <hip/hip_runtime.h>
#include <math.h>

constexpr int C   = 128;
constexpr int HW  = 784;   // 28*28
constexpr int PW  = 30;    // padded row
constexpr int PHW = 900;   // 30*30

// --- repack: w2/a2 [co][ci][3][3] -> [ci][k][co]; w1/a1 [co][ci] -> [ci][co] ---
__global__ __launch_bounds__(256) void reorder_w(const float* __restrict__ w2,
                                                 const float* __restrict__ a2,
                                                 const float* __restrict__ w1,
                                                 const float* __restrict__ a1,
                                                 float* __restrict__ w2r,
                                                 float* __restrict__ a2r,
                                                 float* __restrict__ w1r,
                                                 float* __restrict__ a1r) {
    int idx = blockIdx.x * 256 + threadIdx.x;
    const int T9 = C * C * 9;
    const int T1 = C * C;
    if (idx < 2 * T9) {
        const float* src = w2; float* dst = w2r;
        if (idx >= T9) { idx -= T9; src = a2; dst = a2r; }
        int co = idx & 127;
        int r  = idx >> 7;                // ci*9 + k
        int k  = r % 9;
        int ci = r / 9;
        dst[idx] = src[(co * C + ci) * 9 + k];
        return;
    }
    idx -= 2 * T9;
    if (idx >= 2 * T1) return;
    const float* src = w1; float* dst = w1r;
    if (idx >= T1) { idx -= T1; src = a1; dst = a1r; }
    int co = idx & 127;
    int ci = idx >> 7;
    dst[idx] = src[co * C + ci];          // [ci][co]
}

// --- stage 1: conv1x1 + adder1x1 + BN1 + ReLU -> t1p (padded) ---
// grid: 784 = n(4) x tile(196, 4 px each); 1024 threads = co(128) x ciq(8, 16 ci)
__global__ __launch_bounds__(1024, 8) void stage1(const float* __restrict__ x,
                                                  const float* __restrict__ w1r,
                                                  const float* __restrict__ a1r,
                                                  const float* __restrict__ g1,
                                                  const float* __restrict__ b1,
                                                  const float* __restrict__ m1,
                                                  const float* __restrict__ v1,
                                                  float* __restrict__ t1p) {
    __shared__ float Xs[C][4];
    __shared__ float Ys[C][4];
    __shared__ float Rs[7][C][4];
    int blk = blockIdx.x;
    int n   = blk / 196;
    int q0  = (blk % 196) * 4;        // linear pixel, rows not crossed (28%4==0)
    int t   = threadIdx.x;
    int co  = t & 127;
    int ciq = t >> 7;
    int ci0 = ciq * 16;

    if (t < 512) {
        int ci = t >> 2, p = t & 3;
        Xs[ci][p] = x[(n * C + ci) * HW + q0 + p];
    }
    __syncthreads();

    float4 acc = make_float4(0.f, 0.f, 0.f, 0.f);
    const float* wp = w1r + co;
#pragma unroll
    for (int i = 0; i < 16; ++i) {
        int ci = ci0 + i;
        float wv = wp[ci * C];
        float4 xv = *reinterpret_cast<const float4*>(&Xs[ci][0]);
        acc.x = fmaf(xv.x, wv, acc.x);
        acc.y = fmaf(xv.y, wv, acc.y);
        acc.z = fmaf(xv.z, wv, acc.z);
        acc.w = fmaf(xv.w, wv, acc.w);
    }
    if (ciq) *reinterpret_cast<float4*>(&Rs[ciq - 1][co][0]) = acc;
    __syncthreads();
    if (ciq == 0) {
#pragma unroll
        for (int q = 0; q < 7; ++q) {
            float4 r = *reinterpret_cast<const float4*>(&Rs[q][co][0]);
            acc.x += r.x; acc.y += r.y; acc.z += r.z; acc.w += r.w;
        }
        *reinterpret_cast<float4*>(&Ys[co][0]) = acc;
    }
    __syncthreads();

    float4 ad = make_float4(0.f, 0.f, 0.f, 0.f);
    const float* ap = a1r + co;
#pragma unroll
    for (int i = 0; i < 16; ++i) {
        int ci = ci0 + i;
        float av = ap[ci * C];
        float4 yv = *reinterpret_cast<const float4*>(&Ys[ci][0]);
        ad.x += fabsf(yv.x - av);
        ad.y += fabsf(yv.y - av);
        ad.z += fabsf(yv.z - av);
        ad.w += fabsf(yv.w - av);
    }
    if (ciq) *reinterpret_cast<float4*>(&Rs[ciq - 1][co][0]) = ad;
    __syncthreads();
    if (ciq == 0) {
#pragma unroll
        for (int q = 0; q < 7; ++q) {
            float4 r = *reinterpret_cast<const float4*>(&Rs[q][co][0]);
            ad.x += r.x; ad.y += r.y; ad.z += r.z; ad.w += r.w;
        }
        float inv = g1[co] / sqrtf(v1[co] + 1e-5f);
        float off = b1[co] - m1[co] * inv;
        int h = q0 / 28, w0 = q0 % 28;
        float* dst = t1p + (n * C + co) * PHW + (h + 1) * PW + (w0 + 1);
        dst[0] = fmaxf(-ad.x * inv + off, 0.f);
        dst[1] = fmaxf(-ad.y * inv + off, 0.f);
        dst[2] = fmaxf(-ad.z * inv + off, 0.f);
        dst[3] = fmaxf(-ad.w * inv + off, 0.f);
    }
}

// --- stage 2: conv3x3 pad 1 -> t2p (padded) ---
// grid: 392 = n(4) x th(14) x tw(7); 1024 threads = co(128) x ciq(8, 16 ci)
// x-halo (wave-uniform) via scalar loads; weights coalesced [ci][k][co]
__global__ __launch_bounds__(1024, 8) void conv3x3(const float* __restrict__ t1p,
                                                   const float* __restrict__ w2r,
                                                   float* __restrict__ t2p) {
    __shared__ float Rs[7][C][8];
    int blk = blockIdx.x;
    int n    = blk / 98;
    int tile = blk % 98;
    int th   = tile / 7, tw = tile % 7;
    int h0   = th * 2, w0 = tw * 4;
    int t   = threadIdx.x;
    int co  = t & 127;
    int ciq = t >> 7;
    int ci0u = __builtin_amdgcn_readfirstlane(ciq * 16);   // wave-uniform ci base

    const float* sp0 = t1p + n * C * PHW + h0 * PW + w0;   // halo origin
    const float* wb  = w2r + co;
    float acc[2][4] = {{0.f,0.f,0.f,0.f},{0.f,0.f,0.f,0.f}};

#pragma unroll 2
    for (int i = 0; i < 16; ++i) {
        int ci = ci0u + i;
        const float* wp = wb + ci * 9 * C;
        float wk[9];
#pragma unroll
        for (int k = 0; k < 9; ++k) wk[k] = wp[k * C];     // coalesced vector loads
        const float* sp = sp0 + ci * PHW;                  // uniform -> s_load
        float xr[4][6];
#pragma unroll
        for (int r = 0; r < 4; ++r)
#pragma unroll
            for (int c = 0; c < 6; ++c) xr[r][c] = sp[r * PW + c];
#pragma unroll
        for (int kh = 0; kh < 3; ++kh)
#pragma unroll
            for (int kw = 0; kw < 3; ++kw) {
                float wv = wk[kh * 3 + kw];
#pragma unroll
                for (int pr = 0; pr < 2; ++pr)
#pragma unroll
                    for (int pc = 0; pc < 4; ++pc)
                        acc[pr][pc] = fmaf(xr[pr + kh][pc + kw], wv, acc[pr][pc]);
            }
    }
    if (ciq) {
        *reinterpret_cast<float4*>(&Rs[ciq - 1][co][0]) = make_float4(acc[0][0], acc[0][1], acc[0][2], acc[0][3]);
        *reinterpret_cast<float4*>(&Rs[ciq - 1][co][4]) = make_float4(acc[1][0], acc[1][1], acc[1][2], acc[1][3]);
    }
    __syncthreads();
    if (ciq == 0) {
#pragma unroll
        for (int q = 0; q < 7; ++q) {
            float4 r0 = *reinterpret_cast<const float4*>(&Rs[q][co][0]);
            float4 r1 = *reinterpret_cast<const float4*>(&Rs[q][co][4]);
            acc[0][0] += r0.x; acc[0][1] += r0.y; acc[0][2] += r0.z; acc[0][3] += r0.w;
            acc[1][0] += r1.x; acc[1][1] += r1.y; acc[1][2] += r1.z; acc[1][3] += r1.w;
        }
        float* dst = t2p + (n * C + co) * PHW + (h0 + 1) * PW + (w0 + 1);
#pragma unroll
        for (int pc = 0; pc < 4; ++pc) dst[pc] = acc[0][pc];
#pragma unroll
        for (int pc = 0; pc < 4; ++pc) dst[PW + pc] = acc[1][pc];
    }
}

// --- stage 3: adder3x3 + BN2 + ReLU + residual + ReLU -> out ---
__global__ __launch_bounds__(1024, 8) void adder3x3(const float* __restrict__ t2p,
                                                    const float* __restrict__ a2r,
                                                    const float* __restrict__ x0,
                                                    const float* __restrict__ g2,
                                                    const float* __restrict__ b2,
                                                    const float* __restrict__ m2,
                                                    const float* __restrict__ v2,
                                                    float* __restrict__ out) {
    __shared__ float Rs[7][C][8];
    int blk = blockIdx.x;
    int n    = blk / 98;
    int tile = blk % 98;
    int th   = tile / 7, tw = tile % 7;
    int h0   = th * 2, w0 = tw * 4;
    int t   = threadIdx.x;
    int co  = t & 127;
    int ciq = t >> 7;
    int ci0u = __builtin_amdgcn_readfirstlane(ciq * 16);

    const float* sp0 = t2p + n * C * PHW + h0 * PW + w0;
    const float* ab  = a2r + co;
    float acc[2][4] = {{0.f,0.f,0.f,0.f},{0.f,0.f,0.f,0.f}};

#pragma unroll 2
    for (int i = 0; i < 16; ++i) {
        int ci = ci0u + i;
        const float* wp = ab + ci * 9 * C;
        float wk[9];
#pragma unroll
        for (int k = 0; k < 9; ++k) wk[k] = wp[k * C];
        const float* sp = sp0 + ci * PHW;
        float xr[4][6];
#pragma unroll
        for (int r = 0; r < 4; ++r)
#pragma unroll
            for (int c = 0; c < 6; ++c) xr[r][c] = sp[r * PW + c];
#pragma unroll
        for (int kh = 0; kh < 3; ++kh)
#pragma unroll
            for (int kw = 0; kw < 3; ++kw) {
                float wv = wk[kh * 3 + kw];
#pragma unroll
                for (int pr = 0; pr < 2; ++pr)
#pragma unroll
                    for (int pc = 0; pc < 4; ++pc)
                        acc[pr][pc] += fabsf(xr[pr + kh][pc + kw] - wv);
            }
    }
    if (ciq) {
        *reinterpret_cast<float4*>(&Rs[ciq - 1][co][0]) = make_float4(acc[0][0], acc[0][1], acc[0][2], acc[0][3]);
        *reinterpret_cast<float4*>(&Rs[ciq - 1][co][4]) = make_float4(acc[1][0], acc[1][1], acc[1][2], acc[1][3]);
    }
    __syncthreads();
    if (ciq == 0) {
#pragma unroll
        for (int q = 0; q < 7; ++q) {
            float4 r0 = *reinterpret_cast<const float4*>(&Rs[q][co][0]);
            float4 r1 = *reinterpret_cast<const float4*>(&Rs[q][co][4]);
            acc[0][0] += r0.x; acc[0][1] += r0.y; acc[0][2] += r0.z; acc[0][3] += r0.w;
            acc[1][0] += r1.x; acc[1][1] += r1.y; acc[1][2] += r1.z; acc[1][3] += r1.w;
        }
        float inv = g2[co] / sqrtf(v2[co] + 1e-5f);
        float off = b2[co] - m2[co] * inv;
        int base = (n * C + co) * HW + h0 * 28 + w0;
#pragma unroll
        for (int pr = 0; pr < 2; ++pr) {
            float4 id = *reinterpret_cast<const float4*>(&x0[base + pr * 28]);
            float4 z;
            z.x = fmaxf(fmaxf(-acc[pr][0] * inv + off, 0.f) + id.x, 0.f);
            z.y = fmaxf(fmaxf(-acc[pr][1] * inv + off, 0.f) + id.y, 0.f);
            z.z = fmaxf(fmaxf(-acc[pr][2] * inv + off, 0.f) + id.z, 0.f);
            z.w = fmaxf(fmaxf(-acc[pr][3] * inv + off, 0.f) + id.w, 0.f);
            *reinterpret_cast<float4*>(&out[base + pr * 28]) = z;
        }
    }
}

extern "C" void kernel_launch(void* const* d_in, const int* in_sizes, int n_in,
                              void* d_out, int out_size, void* d_ws, size_t ws_size,
                              hipStream_t stream) {
    const float* x   = (const float*)d_in[0];
    const float* w1  = (const float*)d_in[1];
    const float* a1  = (const float*)d_in[2];
    const float* g1  = (const float*)d_in[3];
    const float* b1  = (const float*)d_in[4];
    const float* m1  = (const float*)d_in[5];
    const float* v1  = (const float*)d_in[6];
    const float* w2  = (const float*)d_in[7];
    const float* a2  = (const float*)d_in[8];
    const float* g2  = (const float*)d_in[9];
    const float* b2  = (const float*)d_in[10];
    const float* m2  = (const float*)d_in[11];
    const float* v2  = (const float*)d_in[12];
    float* out = (float*)d_out;

    float* ws  = (float*)d_ws;
    float* t1p = ws;                       // 4*128*900 = 460800
    float* t2p = t1p + 4 * C * PHW;        // 460800
    float* w2r = t2p + 4 * C * PHW;        // 147456
    float* a2r = w2r + C * C * 9;          // 147456
    float* w1r = a2r + C * C * 9;          // 16384
    float* a1r = w1r + C * C;              // 16384

    // zero the padded intermediates (borders must be 0 every call)
    hipMemsetAsync(t1p, 0, (size_t)(2 * 4 * C * PHW) * sizeof(float), stream);

    const int reorder_total = 2 * C * C * 9 + 2 * C * C;
    reorder_w<<<(reorder_total + 255) / 256, 256, 0, stream>>>(w2, a2, w1, a1, w2r, a2r, w1r, a1r);
    stage1<<<784, 1024, 0, stream>>>(x, w1r, a1r, g1, b1, m1, v1, t1p);
    conv3x3<<<392, 1024, 0, stream>>>(t1p, w2r, t2p);
    adder3x3<<<392, 1024, 0, stream>>>(t2p, a2r, x, g2, b2, m2, v2, out);
}

// Round 8
// 86.459 us; speedup vs baseline: 2.5116x; 1.0360x over previous
//
#include <hip/hip_runtime.h>
#include <math.h>

constexpr int C   = 128;
constexpr int HW  = 784;   // 28*28
constexpr int PW  = 30;    // padded row
constexpr int PHW = 900;   // 30*30

// Region-swizzled tile map, shared by stage1/conv3x3/adder3x3.
// 392 blocks = 8 regions x 49 tiles. region = wg%8 -> XCD (round-robin),
// region = (n, half-image); tile within region = th_local(7) x tw(7).
// Tile covers output rows h0..h0+1, cols w0..w0+3.
__device__ inline void tile_map(int wg, int& n, int& h0, int& w0) {
    int region = wg & 7;
    int idx    = wg >> 3;            // 0..48
    n = region >> 1;
    int half = region & 1;
    int th = half * 7 + idx / 7;
    int tw = idx % 7;
    h0 = th * 2;
    w0 = tw * 4;
}

// --- repack: w2/a2 [co][ci][3][3] -> [ci][k][co]; w1/a1 [co][ci] -> [ci][co] ---
__global__ __launch_bounds__(256) void reorder_w(const float* __restrict__ w2,
                                                 const float* __restrict__ a2,
                                                 const float* __restrict__ w1,
                                                 const float* __restrict__ a1,
                                                 float* __restrict__ w2r,
                                                 float* __restrict__ a2r,
                                                 float* __restrict__ w1r,
                                                 float* __restrict__ a1r) {
    int idx = blockIdx.x * 256 + threadIdx.x;
    const int T9 = C * C * 9;
    const int T1 = C * C;
    if (idx < 2 * T9) {
        const float* src = w2; float* dst = w2r;
        if (idx >= T9) { idx -= T9; src = a2; dst = a2r; }
        int co = idx & 127;
        int r  = idx >> 7;                // ci*9 + k
        int k  = r % 9;
        int ci = r / 9;
        dst[idx] = src[(co * C + ci) * 9 + k];
        return;
    }
    idx -= 2 * T9;
    if (idx >= 2 * T1) return;
    const float* src = w1; float* dst = w1r;
    if (idx >= T1) { idx -= T1; src = a1; dst = a1r; }
    int co = idx & 127;
    int ci = idx >> 7;
    dst[idx] = src[co * C + ci];          // [ci][co]
}

// --- stage 1: conv1x1 + adder1x1 + BN1 + ReLU -> t1p (padded) ---
// grid: 392 swizzled tiles (2x4 px); 1024 threads = co(128) x ciq(8, 16 ci)
__global__ __launch_bounds__(1024, 8) void stage1(const float* __restrict__ x,
                                                  const float* __restrict__ w1r,
                                                  const float* __restrict__ a1r,
                                                  const float* __restrict__ g1,
                                                  const float* __restrict__ b1,
                                                  const float* __restrict__ m1,
                                                  const float* __restrict__ v1,
                                                  float* __restrict__ t1p) {
    __shared__ float Xs[C][8];        // [ci][px]  px = r*4+c
    __shared__ float Ys[C][8];        // conv output [co][px]
    __shared__ float Rs[7][C][8];
    int n, h0, w0;
    tile_map(blockIdx.x, n, h0, w0);
    int t   = threadIdx.x;
    int co  = t & 127;
    int ciq = t >> 7;
    int ci0 = ciq * 16;

    {   // one element per thread: 128 ci x 8 px
        int ci = t >> 3, p = t & 7, r = p >> 2, c = p & 3;
        Xs[ci][p] = x[(n * C + ci) * HW + (h0 + r) * 28 + w0 + c];
    }
    __syncthreads();

    float4 a0 = make_float4(0.f,0.f,0.f,0.f), a1v = make_float4(0.f,0.f,0.f,0.f);
    const float* wp = w1r + co;
#pragma unroll
    for (int i = 0; i < 16; ++i) {
        int ci = ci0 + i;
        float wv = wp[ci * C];
        float4 lo = *reinterpret_cast<const float4*>(&Xs[ci][0]);
        float4 hi = *reinterpret_cast<const float4*>(&Xs[ci][4]);
        a0.x = fmaf(lo.x, wv, a0.x); a0.y = fmaf(lo.y, wv, a0.y);
        a0.z = fmaf(lo.z, wv, a0.z); a0.w = fmaf(lo.w, wv, a0.w);
        a1v.x = fmaf(hi.x, wv, a1v.x); a1v.y = fmaf(hi.y, wv, a1v.y);
        a1v.z = fmaf(hi.z, wv, a1v.z); a1v.w = fmaf(hi.w, wv, a1v.w);
    }
    if (ciq) {
        *reinterpret_cast<float4*>(&Rs[ciq - 1][co][0]) = a0;
        *reinterpret_cast<float4*>(&Rs[ciq - 1][co][4]) = a1v;
    }
    __syncthreads();
    if (ciq == 0) {
#pragma unroll
        for (int q = 0; q < 7; ++q) {
            float4 r0 = *reinterpret_cast<const float4*>(&Rs[q][co][0]);
            float4 r1 = *reinterpret_cast<const float4*>(&Rs[q][co][4]);
            a0.x += r0.x; a0.y += r0.y; a0.z += r0.z; a0.w += r0.w;
            a1v.x += r1.x; a1v.y += r1.y; a1v.z += r1.z; a1v.w += r1.w;
        }
        *reinterpret_cast<float4*>(&Ys[co][0]) = a0;
        *reinterpret_cast<float4*>(&Ys[co][4]) = a1v;
    }
    __syncthreads();

    float4 d0 = make_float4(0.f,0.f,0.f,0.f), d1 = make_float4(0.f,0.f,0.f,0.f);
    const float* ap = a1r + co;
#pragma unroll
    for (int i = 0; i < 16; ++i) {
        int ci = ci0 + i;
        float av = ap[ci * C];
        float4 lo = *reinterpret_cast<const float4*>(&Ys[ci][0]);
        float4 hi = *reinterpret_cast<const float4*>(&Ys[ci][4]);
        d0.x += fabsf(lo.x - av); d0.y += fabsf(lo.y - av);
        d0.z += fabsf(lo.z - av); d0.w += fabsf(lo.w - av);
        d1.x += fabsf(hi.x - av); d1.y += fabsf(hi.y - av);
        d1.z += fabsf(hi.z - av); d1.w += fabsf(hi.w - av);
    }
    if (ciq) {
        *reinterpret_cast<float4*>(&Rs[ciq - 1][co][0]) = d0;
        *reinterpret_cast<float4*>(&Rs[ciq - 1][co][4]) = d1;
    }
    __syncthreads();
    if (ciq == 0) {
#pragma unroll
        for (int q = 0; q < 7; ++q) {
            float4 r0 = *reinterpret_cast<const float4*>(&Rs[q][co][0]);
            float4 r1 = *reinterpret_cast<const float4*>(&Rs[q][co][4]);
            d0.x += r0.x; d0.y += r0.y; d0.z += r0.z; d0.w += r0.w;
            d1.x += r1.x; d1.y += r1.y; d1.z += r1.z; d1.w += r1.w;
        }
        float inv = g1[co] / sqrtf(v1[co] + 1e-5f);
        float off = b1[co] - m1[co] * inv;
        float* dst = t1p + (n * C + co) * PHW + (h0 + 1) * PW + (w0 + 1);
        dst[0] = fmaxf(-d0.x * inv + off, 0.f);
        dst[1] = fmaxf(-d0.y * inv + off, 0.f);
        dst[2] = fmaxf(-d0.z * inv + off, 0.f);
        dst[3] = fmaxf(-d0.w * inv + off, 0.f);
        dst[PW + 0] = fmaxf(-d1.x * inv + off, 0.f);
        dst[PW + 1] = fmaxf(-d1.y * inv + off, 0.f);
        dst[PW + 2] = fmaxf(-d1.z * inv + off, 0.f);
        dst[PW + 3] = fmaxf(-d1.w * inv + off, 0.f);
    }
}

// --- stage 2: conv3x3 pad 1 -> t2p (padded) ---
// grid: 392 swizzled tiles; 1024 threads = co(128) x ciq(8, 16 ci)
__global__ __launch_bounds__(1024, 8) void conv3x3(const float* __restrict__ t1p,
                                                   const float* __restrict__ w2r,
                                                   float* __restrict__ t2p) {
    __shared__ float Rs[7][C][8];
    int n, h0, w0;
    tile_map(blockIdx.x, n, h0, w0);
    int t   = threadIdx.x;
    int co  = t & 127;
    int ciq = t >> 7;
    int ci0u = __builtin_amdgcn_readfirstlane(ciq * 16);

    const float* sp0 = t1p + n * C * PHW + h0 * PW + w0;
    const float* wb  = w2r + co;
    float acc[2][4] = {{0.f,0.f,0.f,0.f},{0.f,0.f,0.f,0.f}};

#pragma unroll 2
    for (int i = 0; i < 16; ++i) {
        int ci = ci0u + i;
        const float* wp = wb + ci * 9 * C;
        float wk[9];
#pragma unroll
        for (int k = 0; k < 9; ++k) wk[k] = wp[k * C];
        const float* sp = sp0 + ci * PHW;
        float xr[4][6];
#pragma unroll
        for (int r = 0; r < 4; ++r)
#pragma unroll
            for (int c = 0; c < 6; ++c) xr[r][c] = sp[r * PW + c];
#pragma unroll
        for (int kh = 0; kh < 3; ++kh)
#pragma unroll
            for (int kw = 0; kw < 3; ++kw) {
                float wv = wk[kh * 3 + kw];
#pragma unroll
                for (int pr = 0; pr < 2; ++pr)
#pragma unroll
                    for (int pc = 0; pc < 4; ++pc)
                        acc[pr][pc] = fmaf(xr[pr + kh][pc + kw], wv, acc[pr][pc]);
            }
    }
    if (ciq) {
        *reinterpret_cast<float4*>(&Rs[ciq - 1][co][0]) = make_float4(acc[0][0], acc[0][1], acc[0][2], acc[0][3]);
        *reinterpret_cast<float4*>(&Rs[ciq - 1][co][4]) = make_float4(acc[1][0], acc[1][1], acc[1][2], acc[1][3]);
    }
    __syncthreads();
    if (ciq == 0) {
#pragma unroll
        for (int q = 0; q < 7; ++q) {
            float4 r0 = *reinterpret_cast<const float4*>(&Rs[q][co][0]);
            float4 r1 = *reinterpret_cast<const float4*>(&Rs[q][co][4]);
            acc[0][0] += r0.x; acc[0][1] += r0.y; acc[0][2] += r0.z; acc[0][3] += r0.w;
            acc[1][0] += r1.x; acc[1][1] += r1.y; acc[1][2] += r1.z; acc[1][3] += r1.w;
        }
        float* dst = t2p + (n * C + co) * PHW + (h0 + 1) * PW + (w0 + 1);
#pragma unroll
        for (int pc = 0; pc < 4; ++pc) dst[pc] = acc[0][pc];
#pragma unroll
        for (int pc = 0; pc < 4; ++pc) dst[PW + pc] = acc[1][pc];
    }
}

// --- stage 3: adder3x3 + BN2 + ReLU + residual + ReLU -> out ---
__global__ __launch_bounds__(1024, 8) void adder3x3(const float* __restrict__ t2p,
                                                    const float* __restrict__ a2r,
                                                    const float* __restrict__ x0,
                                                    const float* __restrict__ g2,
                                                    const float* __restrict__ b2,
                                                    const float* __restrict__ m2,
                                                    const float* __restrict__ v2,
                                                    float* __restrict__ out) {
    __shared__ float Rs[7][C][8];
    int n, h0, w0;
    tile_map(blockIdx.x, n, h0, w0);
    int t   = threadIdx.x;
    int co  = t & 127;
    int ciq = t >> 7;
    int ci0u = __builtin_amdgcn_readfirstlane(ciq * 16);

    const float* sp0 = t2p + n * C * PHW + h0 * PW + w0;
    const float* ab  = a2r + co;
    float acc[2][4] = {{0.f,0.f,0.f,0.f},{0.f,0.f,0.f,0.f}};

#pragma unroll 2
    for (int i = 0; i < 16; ++i) {
        int ci = ci0u + i;
        const float* wp = ab + ci * 9 * C;
        float wk[9];
#pragma unroll
        for (int k = 0; k < 9; ++k) wk[k] = wp[k * C];
        const float* sp = sp0 + ci * PHW;
        float xr[4][6];
#pragma unroll
        for (int r = 0; r < 4; ++r)
#pragma unroll
            for (int c = 0; c < 6; ++c) xr[r][c] = sp[r * PW + c];
#pragma unroll
        for (int kh = 0; kh < 3; ++kh)
#pragma unroll
            for (int kw = 0; kw < 3; ++kw) {
                float wv = wk[kh * 3 + kw];
#pragma unroll
                for (int pr = 0; pr < 2; ++pr)
#pragma unroll
                    for (int pc = 0; pc < 4; ++pc)
                        acc[pr][pc] += fabsf(xr[pr + kh][pc + kw] - wv);
            }
    }
    if (ciq) {
        *reinterpret_cast<float4*>(&Rs[ciq - 1][co][0]) = make_float4(acc[0][0], acc[0][1], acc[0][2], acc[0][3]);
        *reinterpret_cast<float4*>(&Rs[ciq - 1][co][4]) = make_float4(acc[1][0], acc[1][1], acc[1][2], acc[1][3]);
    }
    __syncthreads();
    if (ciq == 0) {
#pragma unroll
        for (int q = 0; q < 7; ++q) {
            float4 r0 = *reinterpret_cast<const float4*>(&Rs[q][co][0]);
            float4 r1 = *reinterpret_cast<const float4*>(&Rs[q][co][4]);
            acc[0][0] += r0.x; acc[0][1] += r0.y; acc[0][2] += r0.z; acc[0][3] += r0.w;
            acc[1][0] += r1.x; acc[1][1] += r1.y; acc[1][2] += r1.z; acc[1][3] += r1.w;
        }
        float inv = g2[co] / sqrtf(v2[co] + 1e-5f);
        float off = b2[co] - m2[co] * inv;
        int base = (n * C + co) * HW + h0 * 28 + w0;
#pragma unroll
        for (int pr = 0; pr < 2; ++pr) {
#pragma unroll
            for (int pc = 0; pc < 4; ++pc) {
                float z = fmaxf(-acc[pr][pc] * inv + off, 0.f);
                z += x0[base + pr * 28 + pc];
                out[base + pr * 28 + pc] = fmaxf(z, 0.f);
            }
        }
    }
}

extern "C" void kernel_launch(void* const* d_in, const int* in_sizes, int n_in,
                              void* d_out, int out_size, void* d_ws, size_t ws_size,
                              hipStream_t stream) {
    const float* x   = (const float*)d_in[0];
    const float* w1  = (const float*)d_in[1];
    const float* a1  = (const float*)d_in[2];
    const float* g1  = (const float*)d_in[3];
    const float* b1  = (const float*)d_in[4];
    const float* m1  = (const float*)d_in[5];
    const float* v1  = (const float*)d_in[6];
    const float* w2  = (const float*)d_in[7];
    const float* a2  = (const float*)d_in[8];
    const float* g2  = (const float*)d_in[9];
    const float* b2  = (const float*)d_in[10];
    const float* m2  = (const float*)d_in[11];
    const float* v2  = (const float*)d_in[12];
    float* out = (float*)d_out;

    float* ws  = (float*)d_ws;
    float* t1p = ws;                       // 4*128*900 = 460800
    float* t2p = t1p + 4 * C * PHW;        // 460800
    float* w2r = t2p + 4 * C * PHW;        // 147456
    float* a2r = w2r + C * C * 9;          // 147456
    float* w1r = a2r + C * C * 9;          // 16384
    float* a1r = w1r + C * C;              // 16384

    // zero the padded intermediates (borders must be 0 every call)
    hipMemsetAsync(t1p, 0, (size_t)(2 * 4 * C * PHW) * sizeof(float), stream);

    const int reorder_total = 2 * C * C * 9 + 2 * C * C;
    reorder_w<<<(reorder_total + 255) / 256, 256, 0, stream>>>(w2, a2, w1, a1, w2r, a2r, w1r, a1r);
    stage1<<<392, 1024, 0, stream>>>(x, w1r, a1r, g1, b1, m1, v1, t1p);
    conv3x3<<<392, 1024, 0, stream>>>(t1p, w2r, t2p);
    adder3x3<<<392, 1024, 0, stream>>>(t2p, a2r, x, g2, b2, m2, v2, out);
}

// Round 9
// 80.652 us; speedup vs baseline: 2.6924x; 1.0720x over previous
//
#include <hip/hip_runtime.h>
#include <math.h>

constexpr int C   = 128;
constexpr int HW  = 784;   // 28*28
constexpr int PW  = 30;    // padded row
constexpr int PHW = 900;   // 30*30

// guaranteed 2-instr L1 tap: v_sub + v_add with abs() source modifier
#define ABS_ACC(acc, d) asm("v_add_f32 %0, %0, abs(%1)" : "+v"(acc) : "v"(d))

// 784 blocks = 8 regions (XCD round-robin) x 98 tiles; 2x2-px tiles on 14x14/img
__device__ inline void tile_map(int wg, int& n, int& h0, int& w0) {
    int region = wg & 7;
    int idx    = wg >> 3;            // 0..97
    n = region >> 1;
    int half = region & 1;
    int th = half * 7 + idx / 14;    // 0..13
    int tw = idx % 14;               // 0..13
    h0 = th * 2;
    w0 = tw * 2;
}

// zero the pad border cells adjacent to this 2x2 tile (plane = one padded 30x30)
__device__ inline void zero_border(float* plane, int h0, int w0) {
    if (h0 == 0) {
        plane[w0 + 1] = 0.f; plane[w0 + 2] = 0.f;
        if (w0 == 0)  plane[0]  = 0.f;
        if (w0 == 26) plane[29] = 0.f;
    }
    if (h0 == 26) {
        plane[29 * PW + w0 + 1] = 0.f; plane[29 * PW + w0 + 2] = 0.f;
        if (w0 == 0)  plane[29 * PW]      = 0.f;
        if (w0 == 26) plane[29 * PW + 29] = 0.f;
    }
    if (w0 == 0)  { plane[(h0 + 1) * PW]      = 0.f; plane[(h0 + 2) * PW]      = 0.f; }
    if (w0 == 26) { plane[(h0 + 1) * PW + 29] = 0.f; plane[(h0 + 2) * PW + 29] = 0.f; }
}

// --- repack: w2/a2 [co][ci][3][3] -> [ci][k][co]; w1/a1 [co][ci] -> [ci][co] ---
__global__ __launch_bounds__(256) void reorder_w(const float* __restrict__ w2,
                                                 const float* __restrict__ a2,
                                                 const float* __restrict__ w1,
                                                 const float* __restrict__ a1,
                                                 float* __restrict__ w2r,
                                                 float* __restrict__ a2r,
                                                 float* __restrict__ w1r,
                                                 float* __restrict__ a1r) {
    int idx = blockIdx.x * 256 + threadIdx.x;
    const int T9 = C * C * 9;
    const int T1 = C * C;
    if (idx < 2 * T9) {
        const float* src = w2; float* dst = w2r;
        if (idx >= T9) { idx -= T9; src = a2; dst = a2r; }
        int co = idx & 127;
        int r  = idx >> 7;                // ci*9 + k
        int k  = r % 9;
        int ci = r / 9;
        dst[idx] = src[(co * C + ci) * 9 + k];
        return;
    }
    idx -= 2 * T9;
    if (idx >= 2 * T1) return;
    const float* src = w1; float* dst = w1r;
    if (idx >= T1) { idx -= T1; src = a1; dst = a1r; }
    int co = idx & 127;
    int ci = idx >> 7;
    dst[idx] = src[co * C + ci];          // [ci][co]
}

// --- stage 1: conv1x1 + adder1x1 + BN1 + ReLU -> t1p (padded, borders zeroed) ---
// 784 blocks x 256 threads = co(128) x ciq(2, 64 ci each); 2x2 px per block
__global__ __launch_bounds__(256, 8) void stage1(const float* __restrict__ x,
                                                 const float* __restrict__ w1r,
                                                 const float* __restrict__ a1r,
                                                 const float* __restrict__ g1,
                                                 const float* __restrict__ b1,
                                                 const float* __restrict__ m1,
                                                 const float* __restrict__ v1,
                                                 float* __restrict__ t1p) {
    __shared__ float Xs[C][4];        // [ci][px], px = r*2+c
    __shared__ float Ys[C][4];        // conv output [co][px]
    __shared__ float Rs[C][4];        // ciq=1 partials
    int n, h0, w0;
    tile_map(blockIdx.x, n, h0, w0);
    int t   = threadIdx.x;
    int co  = t & 127;
    int ciq = t >> 7;                 // 0..1
    int ci0 = ciq * 64;

#pragma unroll
    for (int e = t; e < 512; e += 256) {
        int ci = e >> 2, p = e & 3, r = p >> 1, c = p & 1;
        Xs[ci][p] = x[(n * C + ci) * HW + (h0 + r) * 28 + w0 + c];
    }
    __syncthreads();

    float4 a = make_float4(0.f, 0.f, 0.f, 0.f);
    const float* wp = w1r + co;
#pragma unroll 4
    for (int i = 0; i < 64; ++i) {
        int ci = ci0 + i;
        float wv = wp[ci * C];                                    // coalesced
        float4 xv = *reinterpret_cast<const float4*>(&Xs[ci][0]); // broadcast
        a.x = fmaf(xv.x, wv, a.x);
        a.y = fmaf(xv.y, wv, a.y);
        a.z = fmaf(xv.z, wv, a.z);
        a.w = fmaf(xv.w, wv, a.w);
    }
    if (ciq) *reinterpret_cast<float4*>(&Rs[co][0]) = a;
    __syncthreads();
    if (ciq == 0) {
        float4 r = *reinterpret_cast<const float4*>(&Rs[co][0]);
        a.x += r.x; a.y += r.y; a.z += r.z; a.w += r.w;
        *reinterpret_cast<float4*>(&Ys[co][0]) = a;
    }
    __syncthreads();

    float d0 = 0.f, d1 = 0.f, d2 = 0.f, d3 = 0.f;
    const float* ap = a1r + co;
#pragma unroll 4
    for (int i = 0; i < 64; ++i) {
        int ci = ci0 + i;
        float av = ap[ci * C];
        float4 yv = *reinterpret_cast<const float4*>(&Ys[ci][0]);
        float e0 = yv.x - av; ABS_ACC(d0, e0);
        float e1 = yv.y - av; ABS_ACC(d1, e1);
        float e2 = yv.z - av; ABS_ACC(d2, e2);
        float e3 = yv.w - av; ABS_ACC(d3, e3);
    }
    if (ciq) *reinterpret_cast<float4*>(&Rs[co][0]) = make_float4(d0, d1, d2, d3);
    __syncthreads();
    if (ciq == 0) {
        float4 r = *reinterpret_cast<const float4*>(&Rs[co][0]);
        d0 += r.x; d1 += r.y; d2 += r.z; d3 += r.w;
        float inv = g1[co] / sqrtf(v1[co] + 1e-5f);
        float off = b1[co] - m1[co] * inv;
        float* plane = t1p + (n * C + co) * PHW;
        float* dst = plane + (h0 + 1) * PW + (w0 + 1);
        dst[0]      = fmaxf(-d0 * inv + off, 0.f);
        dst[1]      = fmaxf(-d1 * inv + off, 0.f);
        dst[PW + 0] = fmaxf(-d2 * inv + off, 0.f);
        dst[PW + 1] = fmaxf(-d3 * inv + off, 0.f);
        zero_border(plane, h0, w0);
    }
}

// --- stage 2: conv3x3 pad 1 -> t2p (padded, borders zeroed) ---
// 784 blocks x 256 threads = co(128) x ciq(2, 64 ci each); 2x2 px per block
__global__ __launch_bounds__(256, 8) void conv3x3(const float* __restrict__ t1p,
                                                  const float* __restrict__ w2r,
                                                  float* __restrict__ t2p) {
    __shared__ float Rs[C][4];
    int n, h0, w0;
    tile_map(blockIdx.x, n, h0, w0);
    int t   = threadIdx.x;
    int co  = t & 127;
    int ciq = t >> 7;
    int ci0u = __builtin_amdgcn_readfirstlane(ciq * 64);

    const float* sp0 = t1p + n * C * PHW + h0 * PW + w0;   // 4x4 halo origin
    const float* wb  = w2r + co;
    float acc[4] = {0.f, 0.f, 0.f, 0.f};

#pragma unroll 2
    for (int i = 0; i < 64; ++i) {
        int ci = ci0u + i;
        const float* wp = wb + ci * 9 * C;
        float wk[9];
#pragma unroll
        for (int k = 0; k < 9; ++k) wk[k] = wp[k * C];     // coalesced b32
        const float* sp = sp0 + ci * PHW;                  // uniform -> s_load
        float xr[4][4];
#pragma unroll
        for (int r = 0; r < 4; ++r)
#pragma unroll
            for (int c = 0; c < 4; ++c) xr[r][c] = sp[r * PW + c];
#pragma unroll
        for (int kh = 0; kh < 3; ++kh)
#pragma unroll
            for (int kw = 0; kw < 3; ++kw) {
                float wv = wk[kh * 3 + kw];
                acc[0] = fmaf(xr[kh + 0][kw + 0], wv, acc[0]);
                acc[1] = fmaf(xr[kh + 0][kw + 1], wv, acc[1]);
                acc[2] = fmaf(xr[kh + 1][kw + 0], wv, acc[2]);
                acc[3] = fmaf(xr[kh + 1][kw + 1], wv, acc[3]);
            }
    }
    if (ciq) *reinterpret_cast<float4*>(&Rs[co][0]) = make_float4(acc[0], acc[1], acc[2], acc[3]);
    __syncthreads();
    if (ciq == 0) {
        float4 r = *reinterpret_cast<const float4*>(&Rs[co][0]);
        acc[0] += r.x; acc[1] += r.y; acc[2] += r.z; acc[3] += r.w;
        float* plane = t2p + (n * C + co) * PHW;
        float* dst = plane + (h0 + 1) * PW + (w0 + 1);
        dst[0]      = acc[0];
        dst[1]      = acc[1];
        dst[PW + 0] = acc[2];
        dst[PW + 1] = acc[3];
        zero_border(plane, h0, w0);
    }
}

// --- stage 3: adder3x3 + BN2 + ReLU + residual + ReLU -> out ---
__global__ __launch_bounds__(256, 8) void adder3x3(const float* __restrict__ t2p,
                                                   const float* __restrict__ a2r,
                                                   const float* __restrict__ x0,
                                                   const float* __restrict__ g2,
                                                   const float* __restrict__ b2,
                                                   const float* __restrict__ m2,
                                                   const float* __restrict__ v2,
                                                   float* __restrict__ out) {
    __shared__ float Rs[C][4];
    int n, h0, w0;
    tile_map(blockIdx.x, n, h0, w0);
    int t   = threadIdx.x;
    int co  = t & 127;
    int ciq = t >> 7;
    int ci0u = __builtin_amdgcn_readfirstlane(ciq * 64);

    const float* sp0 = t2p + n * C * PHW + h0 * PW + w0;
    const float* ab  = a2r + co;
    float acc[4] = {0.f, 0.f, 0.f, 0.f};

#pragma unroll 2
    for (int i = 0; i < 64; ++i) {
        int ci = ci0u + i;
        const float* wp = ab + ci * 9 * C;
        float wk[9];
#pragma unroll
        for (int k = 0; k < 9; ++k) wk[k] = wp[k * C];
        const float* sp = sp0 + ci * PHW;
        float xr[4][4];
#pragma unroll
        for (int r = 0; r < 4; ++r)
#pragma unroll
            for (int c = 0; c < 4; ++c) xr[r][c] = sp[r * PW + c];
#pragma unroll
        for (int kh = 0; kh < 3; ++kh)
#pragma unroll
            for (int kw = 0; kw < 3; ++kw) {
                float wv = wk[kh * 3 + kw];
                float e0 = xr[kh + 0][kw + 0] - wv; ABS_ACC(acc[0], e0);
                float e1 = xr[kh + 0][kw + 1] - wv; ABS_ACC(acc[1], e1);
                float e2 = xr[kh + 1][kw + 0] - wv; ABS_ACC(acc[2], e2);
                float e3 = xr[kh + 1][kw + 1] - wv; ABS_ACC(acc[3], e3);
            }
    }
    if (ciq) *reinterpret_cast<float4*>(&Rs[co][0]) = make_float4(acc[0], acc[1], acc[2], acc[3]);
    __syncthreads();
    if (ciq == 0) {
        float4 r = *reinterpret_cast<const float4*>(&Rs[co][0]);
        acc[0] += r.x; acc[1] += r.y; acc[2] += r.z; acc[3] += r.w;
        float inv = g2[co] / sqrtf(v2[co] + 1e-5f);
        float off = b2[co] - m2[co] * inv;
        int base = (n * C + co) * HW + h0 * 28 + w0;
        float z0 = fmaxf(-acc[0] * inv + off, 0.f) + x0[base + 0];
        float z1 = fmaxf(-acc[1] * inv + off, 0.f) + x0[base + 1];
        float z2 = fmaxf(-acc[2] * inv + off, 0.f) + x0[base + 28];
        float z3 = fmaxf(-acc[3] * inv + off, 0.f) + x0[base + 29];
        out[base + 0]  = fmaxf(z0, 0.f);
        out[base + 1]  = fmaxf(z1, 0.f);
        out[base + 28] = fmaxf(z2, 0.f);
        out[base + 29] = fmaxf(z3, 0.f);
    }
}

extern "C" void kernel_launch(void* const* d_in, const int* in_sizes, int n_in,
                              void* d_out, int out_size, void* d_ws, size_t ws_size,
                              hipStream_t stream) {
    const float* x   = (const float*)d_in[0];
    const float* w1  = (const float*)d_in[1];
    const float* a1  = (const float*)d_in[2];
    const float* g1  = (const float*)d_in[3];
    const float* b1  = (const float*)d_in[4];
    const float* m1  = (const float*)d_in[5];
    const float* v1  = (const float*)d_in[6];
    const float* w2  = (const float*)d_in[7];
    const float* a2  = (const float*)d_in[8];
    const float* g2  = (const float*)d_in[9];
    const float* b2  = (const float*)d_in[10];
    const float* m2  = (const float*)d_in[11];
    const float* v2  = (const float*)d_in[12];
    float* out = (float*)d_out;

    float* ws  = (float*)d_ws;
    float* t1p = ws;                       // 460800
    float* t2p = t1p + 4 * C * PHW;        // 460800
    float* w2r = t2p + 4 * C * PHW;        // 147456
    float* a2r = w2r + C * C * 9;          // 147456
    float* w1r = a2r + C * C * 9;          // 16384
    float* a1r = w1r + C * C;              // 16384

    const int reorder_total = 2 * C * C * 9 + 2 * C * C;
    reorder_w<<<(reorder_total + 255) / 256, 256, 0, stream>>>(w2, a2, w1, a1, w2r, a2r, w1r, a1r);
    stage1<<<784, 256, 0, stream>>>(x, w1r, a1r, g1, b1, m1, v1, t1p);
    conv3x3<<<784, 256, 0, stream>>>(t1p, w2r, t2p);
    adder3x3<<<784, 256, 0, stream>>>(t2p, a2r, x, g2, b2, m2, v2, out);
}

// Round 10
// 69.371 us; speedup vs baseline: 3.1303x; 1.1626x over previous
//
#include <hip/hip_runtime.h>
#include <math.h>

constexpr int C   = 128;
constexpr int HW  = 784;   // 28*28
constexpr int PW  = 30;    // padded row
constexpr int PHW = 900;   // 30*30

// guaranteed 2-instr L1 tap: v_sub + v_add with abs() source modifier
#define ABS_ACC(acc, d) asm("v_add_f32 %0, %0, abs(%1)" : "+v"(acc) : "v"(d))

// stage1 map: 784 blocks = 8 regions x 98 tiles of 2x2 px (14x14 per image)
__device__ inline void tile_map2(int wg, int& n, int& h0, int& w0) {
    int region = wg & 7;
    int idx    = wg >> 3;            // 0..97
    n = region >> 1;
    int half = region & 1;
    int th = half * 7 + idx / 14;    // 0..13
    int tw = idx % 14;               // 0..13
    h0 = th * 2;
    w0 = tw * 2;
}

// conv/adder map: 784 blocks = 8 regions x {cohalf(2) x 49 tiles of 2x4 px}
// region = (n, image-half); same region->XCD mapping as stage1 for L2 locality
__device__ inline void tile_map4(int wg, int& n, int& h0, int& w0, int& co0) {
    int region = wg & 7;
    int rest   = wg >> 3;            // 0..97
    n = region >> 1;
    int half = region & 1;
    co0 = (rest & 1) * 64;
    int idx = rest >> 1;             // 0..48
    int th = idx / 7, tw = idx % 7;
    h0 = half * 14 + th * 2;
    w0 = tw * 4;
}

// zero pad-border cells adjacent to a 2x2 tile
__device__ inline void zero_border2(float* plane, int h0, int w0) {
    if (h0 == 0) {
        plane[w0 + 1] = 0.f; plane[w0 + 2] = 0.f;
        if (w0 == 0)  plane[0]  = 0.f;
        if (w0 == 26) plane[29] = 0.f;
    }
    if (h0 == 26) {
        plane[29 * PW + w0 + 1] = 0.f; plane[29 * PW + w0 + 2] = 0.f;
        if (w0 == 0)  plane[29 * PW]      = 0.f;
        if (w0 == 26) plane[29 * PW + 29] = 0.f;
    }
    if (w0 == 0)  { plane[(h0 + 1) * PW]      = 0.f; plane[(h0 + 2) * PW]      = 0.f; }
    if (w0 == 26) { plane[(h0 + 1) * PW + 29] = 0.f; plane[(h0 + 2) * PW + 29] = 0.f; }
}

// zero pad-border cells adjacent to a 2x4 tile
__device__ inline void zero_border4(float* plane, int h0, int w0) {
    if (h0 == 0) {
#pragma unroll
        for (int c = 0; c < 4; ++c) plane[w0 + 1 + c] = 0.f;
        if (w0 == 0)  plane[0]  = 0.f;
        if (w0 == 24) plane[29] = 0.f;
    }
    if (h0 == 26) {
#pragma unroll
        for (int c = 0; c < 4; ++c) plane[29 * PW + w0 + 1 + c] = 0.f;
        if (w0 == 0)  plane[29 * PW]      = 0.f;
        if (w0 == 24) plane[29 * PW + 29] = 0.f;
    }
    if (w0 == 0)  { plane[(h0 + 1) * PW]      = 0.f; plane[(h0 + 2) * PW]      = 0.f; }
    if (w0 == 24) { plane[(h0 + 1) * PW + 29] = 0.f; plane[(h0 + 2) * PW + 29] = 0.f; }
}

// --- repack: w2/a2 [co][ci][3][3] -> [ci][k][co]; w1/a1 [co][ci] -> [ci][co] ---
__global__ __launch_bounds__(256) void reorder_w(const float* __restrict__ w2,
                                                 const float* __restrict__ a2,
                                                 const float* __restrict__ w1,
                                                 const float* __restrict__ a1,
                                                 float* __restrict__ w2r,
                                                 float* __restrict__ a2r,
                                                 float* __restrict__ w1r,
                                                 float* __restrict__ a1r) {
    int idx = blockIdx.x * 256 + threadIdx.x;
    const int T9 = C * C * 9;
    const int T1 = C * C;
    if (idx < 2 * T9) {
        const float* src = w2; float* dst = w2r;
        if (idx >= T9) { idx -= T9; src = a2; dst = a2r; }
        int co = idx & 127;
        int r  = idx >> 7;                // ci*9 + k
        int k  = r % 9;
        int ci = r / 9;
        dst[idx] = src[(co * C + ci) * 9 + k];
        return;
    }
    idx -= 2 * T9;
    if (idx >= 2 * T1) return;
    const float* src = w1; float* dst = w1r;
    if (idx >= T1) { idx -= T1; src = a1; dst = a1r; }
    int co = idx & 127;
    int ci = idx >> 7;
    dst[idx] = src[co * C + ci];          // [ci][co]
}

// --- stage 1: conv1x1 + adder1x1 + BN1 + ReLU -> t1p (padded, borders zeroed) ---
// 784 blocks x 256 threads = co(128) x ciq(2, 64 ci each); 2x2 px per block
__global__ __launch_bounds__(256, 8) void stage1(const float* __restrict__ x,
                                                 const float* __restrict__ w1r,
                                                 const float* __restrict__ a1r,
                                                 const float* __restrict__ g1,
                                                 const float* __restrict__ b1,
                                                 const float* __restrict__ m1,
                                                 const float* __restrict__ v1,
                                                 float* __restrict__ t1p) {
    __shared__ float Xs[C][4];        // [ci][px], px = r*2+c
    __shared__ float Ys[C][4];        // conv output [co][px]
    __shared__ float Rs[C][4];        // ciq=1 partials
    int n, h0, w0;
    tile_map2(blockIdx.x, n, h0, w0);
    int t   = threadIdx.x;
    int co  = t & 127;
    int ciq = t >> 7;                 // 0..1
    int ci0 = ciq * 64;

#pragma unroll
    for (int e = t; e < 512; e += 256) {
        int ci = e >> 2, p = e & 3, r = p >> 1, c = p & 1;
        Xs[ci][p] = x[(n * C + ci) * HW + (h0 + r) * 28 + w0 + c];
    }
    __syncthreads();

    float4 a = make_float4(0.f, 0.f, 0.f, 0.f);
    const float* wp = w1r + co;
#pragma unroll 4
    for (int i = 0; i < 64; ++i) {
        int ci = ci0 + i;
        float wv = wp[ci * C];                                    // coalesced
        float4 xv = *reinterpret_cast<const float4*>(&Xs[ci][0]); // broadcast
        a.x = fmaf(xv.x, wv, a.x);
        a.y = fmaf(xv.y, wv, a.y);
        a.z = fmaf(xv.z, wv, a.z);
        a.w = fmaf(xv.w, wv, a.w);
    }
    if (ciq) *reinterpret_cast<float4*>(&Rs[co][0]) = a;
    __syncthreads();
    if (ciq == 0) {
        float4 r = *reinterpret_cast<const float4*>(&Rs[co][0]);
        a.x += r.x; a.y += r.y; a.z += r.z; a.w += r.w;
        *reinterpret_cast<float4*>(&Ys[co][0]) = a;
    }
    __syncthreads();

    float d0 = 0.f, d1 = 0.f, d2 = 0.f, d3 = 0.f;
    const float* ap = a1r + co;
#pragma unroll 4
    for (int i = 0; i < 64; ++i) {
        int ci = ci0 + i;
        float av = ap[ci * C];
        float4 yv = *reinterpret_cast<const float4*>(&Ys[ci][0]);
        float e0 = yv.x - av; ABS_ACC(d0, e0);
        float e1 = yv.y - av; ABS_ACC(d1, e1);
        float e2 = yv.z - av; ABS_ACC(d2, e2);
        float e3 = yv.w - av; ABS_ACC(d3, e3);
    }
    if (ciq) *reinterpret_cast<float4*>(&Rs[co][0]) = make_float4(d0, d1, d2, d3);
    __syncthreads();
    if (ciq == 0) {
        float4 r = *reinterpret_cast<const float4*>(&Rs[co][0]);
        d0 += r.x; d1 += r.y; d2 += r.z; d3 += r.w;
        float inv = g1[co] / sqrtf(v1[co] + 1e-5f);
        float off = b1[co] - m1[co] * inv;
        float* plane = t1p + (n * C + co) * PHW;
        float* dst = plane + (h0 + 1) * PW + (w0 + 1);
        dst[0]      = fmaxf(-d0 * inv + off, 0.f);
        dst[1]      = fmaxf(-d1 * inv + off, 0.f);
        dst[PW + 0] = fmaxf(-d2 * inv + off, 0.f);
        dst[PW + 1] = fmaxf(-d3 * inv + off, 0.f);
        zero_border2(plane, h0, w0);
    }
}

// --- stage 2: conv3x3 pad 1 -> t2p (padded, borders zeroed) ---
// 784 blocks (co-split 2 x 392 tiles of 2x4 px) x 256 threads = co(64) x ciq(4, 32 ci)
__global__ __launch_bounds__(256, 8) void conv3x3(const float* __restrict__ t1p,
                                                  const float* __restrict__ w2r,
                                                  float* __restrict__ t2p) {
    __shared__ float Rs[3][64][8];
    int n, h0, w0, co0;
    tile_map4(blockIdx.x, n, h0, w0, co0);
    int t   = threadIdx.x;
    int col = t & 63;                 // lane = co within half
    int co  = co0 + col;
    int ciq = t >> 6;                 // 0..3, one wave each
    int ci0u = __builtin_amdgcn_readfirstlane(ciq * 32);

    const float* sp0 = t1p + n * C * PHW + h0 * PW + w0;   // 4x6 halo origin
    const float* wb  = w2r + co;
    float acc[2][4] = {{0.f,0.f,0.f,0.f},{0.f,0.f,0.f,0.f}};

#pragma unroll 2
    for (int i = 0; i < 32; ++i) {
        int ci = ci0u + i;
        const float* wp = wb + ci * 9 * C;
        float wk[9];
#pragma unroll
        for (int k = 0; k < 9; ++k) wk[k] = wp[k * C];     // coalesced 256B
        const float* sp = sp0 + ci * PHW;                  // uniform -> s_load
        float xr[4][6];
#pragma unroll
        for (int r = 0; r < 4; ++r)
#pragma unroll
            for (int c = 0; c < 6; ++c) xr[r][c] = sp[r * PW + c];
#pragma unroll
        for (int kh = 0; kh < 3; ++kh)
#pragma unroll
            for (int kw = 0; kw < 3; ++kw) {
                float wv = wk[kh * 3 + kw];
#pragma unroll
                for (int pr = 0; pr < 2; ++pr)
#pragma unroll
                    for (int pc = 0; pc < 4; ++pc)
                        acc[pr][pc] = fmaf(xr[pr + kh][pc + kw], wv, acc[pr][pc]);
            }
    }
    if (ciq) {
        *reinterpret_cast<float4*>(&Rs[ciq - 1][col][0]) = make_float4(acc[0][0], acc[0][1], acc[0][2], acc[0][3]);
        *reinterpret_cast<float4*>(&Rs[ciq - 1][col][4]) = make_float4(acc[1][0], acc[1][1], acc[1][2], acc[1][3]);
    }
    __syncthreads();
    if (ciq == 0) {
#pragma unroll
        for (int q = 0; q < 3; ++q) {
            float4 r0 = *reinterpret_cast<const float4*>(&Rs[q][col][0]);
            float4 r1 = *reinterpret_cast<const float4*>(&Rs[q][col][4]);
            acc[0][0] += r0.x; acc[0][1] += r0.y; acc[0][2] += r0.z; acc[0][3] += r0.w;
            acc[1][0] += r1.x; acc[1][1] += r1.y; acc[1][2] += r1.z; acc[1][3] += r1.w;
        }
        float* plane = t2p + (n * C + co) * PHW;
        float* dst = plane + (h0 + 1) * PW + (w0 + 1);
#pragma unroll
        for (int pc = 0; pc < 4; ++pc) dst[pc]      = acc[0][pc];
#pragma unroll
        for (int pc = 0; pc < 4; ++pc) dst[PW + pc] = acc[1][pc];
        zero_border4(plane, h0, w0);
    }
}

// --- stage 3: adder3x3 + BN2 + ReLU + residual + ReLU -> out ---
__global__ __launch_bounds__(256, 8) void adder3x3(const float* __restrict__ t2p,
                                                   const float* __restrict__ a2r,
                                                   const float* __restrict__ x0,
                                                   const float* __restrict__ g2,
                                                   const float* __restrict__ b2,
                                                   const float* __restrict__ m2,
                                                   const float* __restrict__ v2,
                                                   float* __restrict__ out) {
    __shared__ float Rs[3][64][8];
    int n, h0, w0, co0;
    tile_map4(blockIdx.x, n, h0, w0, co0);
    int t   = threadIdx.x;
    int col = t & 63;
    int co  = co0 + col;
    int ciq = t >> 6;
    int ci0u = __builtin_amdgcn_readfirstlane(ciq * 32);

    const float* sp0 = t2p + n * C * PHW + h0 * PW + w0;
    const float* ab  = a2r + co;
    float acc[2][4] = {{0.f,0.f,0.f,0.f},{0.f,0.f,0.f,0.f}};

#pragma unroll 2
    for (int i = 0; i < 32; ++i) {
        int ci = ci0u + i;
        const float* wp = ab + ci * 9 * C;
        float wk[9];
#pragma unroll
        for (int k = 0; k < 9; ++k) wk[k] = wp[k * C];
        const float* sp = sp0 + ci * PHW;
        float xr[4][6];
#pragma unroll
        for (int r = 0; r < 4; ++r)
#pragma unroll
            for (int c = 0; c < 6; ++c) xr[r][c] = sp[r * PW + c];
#pragma unroll
        for (int kh = 0; kh < 3; ++kh)
#pragma unroll
            for (int kw = 0; kw < 3; ++kw) {
                float wv = wk[kh * 3 + kw];
#pragma unroll
                for (int pr = 0; pr < 2; ++pr)
#pragma unroll
                    for (int pc = 0; pc < 4; ++pc) {
                        float e = xr[pr + kh][pc + kw] - wv;
                        ABS_ACC(acc[pr][pc], e);
                    }
            }
    }
    if (ciq) {
        *reinterpret_cast<float4*>(&Rs[ciq - 1][col][0]) = make_float4(acc[0][0], acc[0][1], acc[0][2], acc[0][3]);
        *reinterpret_cast<float4*>(&Rs[ciq - 1][col][4]) = make_float4(acc[1][0], acc[1][1], acc[1][2], acc[1][3]);
    }
    __syncthreads();
    if (ciq == 0) {
#pragma unroll
        for (int q = 0; q < 3; ++q) {
            float4 r0 = *reinterpret_cast<const float4*>(&Rs[q][col][0]);
            float4 r1 = *reinterpret_cast<const float4*>(&Rs[q][col][4]);
            acc[0][0] += r0.x; acc[0][1] += r0.y; acc[0][2] += r0.z; acc[0][3] += r0.w;
            acc[1][0] += r1.x; acc[1][1] += r1.y; acc[1][2] += r1.z; acc[1][3] += r1.w;
        }
        float inv = g2[co] / sqrtf(v2[co] + 1e-5f);
        float off = b2[co] - m2[co] * inv;
        int base = (n * C + co) * HW + h0 * 28 + w0;
#pragma unroll
        for (int pr = 0; pr < 2; ++pr) {
#pragma unroll
            for (int pc = 0; pc < 4; ++pc) {
                float z = fmaxf(-acc[pr][pc] * inv + off, 0.f);
                z += x0[base + pr * 28 + pc];
                out[base + pr * 28 + pc] = fmaxf(z, 0.f);
            }
        }
    }
}

extern "C" void kernel_launch(void* const* d_in, const int* in_sizes, int n_in,
                              void* d_out, int out_size, void* d_ws, size_t ws_size,
                              hipStream_t stream) {
    const float* x   = (const float*)d_in[0];
    const float* w1  = (const float*)d_in[1];
    const float* a1  = (const float*)d_in[2];
    const float* g1  = (const float*)d_in[3];
    const float* b1  = (const float*)d_in[4];
    const float* m1  = (const float*)d_in[5];
    const float* v1  = (const float*)d_in[6];
    const float* w2  = (const float*)d_in[7];
    const float* a2  = (const float*)d_in[8];
    const float* g2  = (const float*)d_in[9];
    const float* b2  = (const float*)d_in[10];
    const float* m2  = (const float*)d_in[11];
    const float* v2  = (const float*)d_in[12];
    float* out = (float*)d_out;

    float* ws  = (float*)d_ws;
    float* t1p = ws;                       // 460800
    float* t2p = t1p + 4 * C * PHW;        // 460800
    float* w2r = t2p + 4 * C * PHW;        // 147456
    float* a2r = w2r + C * C * 9;          // 147456
    float* w1r = a2r + C * C * 9;          // 16384
    float* a1r = w1r + C * C;              // 16384

    const int reorder_total = 2 * C * C * 9 + 2 * C * C;
    reorder_w<<<(reorder_total + 255) / 256, 256, 0, stream>>>(w2, a2, w1, a1, w2r, a2r, w1r, a1r);
    stage1<<<784, 256, 0, stream>>>(x, w1r, a1r, g1, b1, m1, v1, t1p);
    conv3x3<<<784, 256, 0, stream>>>(t1p, w2r, t2p);
    adder3x3<<<784, 256, 0, stream>>>(t2p, a2r, x, g2, b2, m2, v2, out);
}